// Round 1
// baseline (8051.770 us; speedup 1.0000x reference)
//
#include <hip/hip_runtime.h>
#include <hip/hip_bf16.h>
#include <stdint.h>

#define B 8
#define T 256
#define DIN 6
#define H 200
#define G 800   // 4*H, ifgo gate order
#define L 200

#define NT 13       // N tiles per gate (208 rows, 200 real)
#define KT 13       // K tiles (416 cols, 400 real)
#define NFRAG 169   // NT*KT fragments per (layer,gate)
#define F_REG 65    // kt 0..4  -> registers (x-part)
#define F_LDS 26    // kt 5..6  -> LDS resident (x-part)
// kt 7..12 streamed (78 frags) == pure-h part (cols 224..415), computed BEFORE the producer wait

// ws layout (float/uint32 elements):
#define OFF_H0    8192                       // h0 as f16 [t][j][b]: B*T*H halves
#define OFF_FINAL (OFF_H0 + (B*T*H)/2)       // final as f32 [b][t][j]
#define OFF_RING  (OFF_FINAL + B*T*H)        // ring as f16 [slot][j][b]
#define PFLAG(l)  ((l) * 16)
#define CFLAG(l)  (4096 + (l) * 16)

typedef _Float16 half8 __attribute__((ext_vector_type(8)));
typedef float f32x4 __attribute__((ext_vector_type(4)));
typedef unsigned long long u64t;

__device__ __forceinline__ float fsig(float x) {
    return 1.0f / (1.0f + __expf(-x));
}
__device__ __forceinline__ float ftanh(float x) {
    float e = __expf(2.0f * x);
    return 1.0f - 2.0f / (e + 1.0f);
}

__device__ __forceinline__ uint32_t ld_flag(const uint32_t* p) {
    return __hip_atomic_load(p, __ATOMIC_RELAXED, __HIP_MEMORY_SCOPE_AGENT);
}
__device__ __forceinline__ void st_flag(uint32_t* p, uint32_t v) {
    __hip_atomic_store(p, v, __ATOMIC_RELAXED, __HIP_MEMORY_SCOPE_AGENT);
}
__device__ __forceinline__ u64t ld_u64(const u64t* p) {
    return __hip_atomic_load(p, __ATOMIC_RELAXED, __HIP_MEMORY_SCOPE_AGENT);
}
__device__ __forceinline__ void st_u64(u64t* p, u64t v) {
    __hip_atomic_store(p, v, __ATOMIC_RELAXED, __HIP_MEMORY_SCOPE_AGENT);
}

__global__ void init_flags(uint32_t* ws) {
    int i = blockIdx.x * 256 + threadIdx.x;
    if (i < 8192) ws[i] = 0u;
}

// mlp1: h0 written as f16 in [t][j][b] layout (ring-compatible for l==0 staging)
__global__ void mlp1_kernel(const float* __restrict__ x, const float* __restrict__ W1,
                            const float* __restrict__ b1, uint16_t* __restrict__ h0h) {
    int idx = blockIdx.x * 256 + threadIdx.x;
    if (idx >= B * T * H) return;
    int j  = idx % H;
    int bt = idx / H;          // bt = b*T + t
    int b  = bt / T;
    int t  = bt % T;
    const float* xr = x  + (size_t)bt * DIN;
    const float* wr = W1 + (size_t)j * DIN;
    float a = b1[j];
#pragma unroll
    for (int k = 0; k < DIN; ++k) a += xr[k] * wr[k];
    _Float16 h = (_Float16)a;
    h0h[((size_t)t * H + j) * B + b] = __builtin_bit_cast(uint16_t, h);
}

// MFMA fragment layout, f16:
// Wm element ((((l*4+g)*KT + kt)*NT + nt)*64 + lane)*8 + j
//   = Wcat[r][k],  r = g*200 + nt*16 + (lane&15),  k = kt*32 + (lane>>4)*8 + j
//   Wcat[r][k] = k<200 ? Wih[l][r][k] : Whh[l][r][k-200]; 0 outside real range.
__global__ void convert_weights_mfma(const float* __restrict__ Wih,
                                     const float* __restrict__ Whh,
                                     uint16_t* __restrict__ Wm) {
    size_t idx = (size_t)blockIdx.x * 256 + threadIdx.x;
    const size_t TOT = (size_t)L * 4 * NFRAG * 64 * 8;
    if (idx >= TOT) return;
    int j    = (int)(idx & 7);
    int lane = (int)((idx >> 3) & 63);
    size_t r0 = idx >> 9;
    int nt = (int)(r0 % NT); r0 /= NT;
    int kt = (int)(r0 % KT); r0 /= KT;
    int g  = (int)(r0 % 4);
    int l  = (int)(r0 / 4);
    int rl = nt * 16 + (lane & 15);
    int k  = kt * 32 + (lane >> 4) * 8 + j;
    float v = 0.0f;
    if (rl < 200 && k < 400) {
        int r = g * 200 + rl;
        v = (k < 200) ? Wih[((size_t)l * G + r) * 200 + k]
                      : Whh[((size_t)l * G + r) * 200 + (k - 200)];
    }
    _Float16 h = (_Float16)v;
    Wm[idx] = __builtin_bit_cast(uint16_t, h);
}

#define MFMA16(a, b, c) __builtin_amdgcn_mfma_f32_16x16x32_f16((a), (b), (c), 0, 0, 0)

// One workgroup per layer, 256 threads = 4 waves, wave w = gate w.
// Per iteration: h-part GEMM (streamed kt7..12, overlaps producer wait) ->
// all-thread flag poll -> f16 u64 stage -> x-part GEMM (reg kt0..4 + LDS kt5..6)
// -> zl exchange -> activation -> packed u64 ring store -> flag.
template <bool FAST>
__global__ __launch_bounds__(256, 1)
void lstm_pipeline(const uint4* __restrict__ Wm,
                   const float* __restrict__ Wih, const float* __restrict__ Whh,
                   const float* __restrict__ bih, const float* __restrict__ bhh,
                   float* ws, int R) {
#pragma clang fp contract(fast)
    const int l     = blockIdx.x;
    const int tid   = threadIdx.x;
    const int wv    = tid >> 6;      // gate index
    const int lane  = tid & 63;
    const int rmask = R - 1;         // R is a power of two

    const uint16_t* h0h = (const uint16_t*)(ws + OFF_H0);
    float*    finalbuf = ws + OFF_FINAL;
    u64t*     ring     = (u64t*)(ws + OFF_RING);   // [slot][j][b] f16, 400 u64/slot
    uint32_t* flags    = (uint32_t*)ws;

    __shared__ __align__(16) _Float16 xh[16 * 416];        // [m][k] A-matrix
    __shared__ __align__(16) float    zl[4 * 8 * 208];     // [g][b][nj]
    __shared__ __align__(16) uint4    wlds[4 * F_LDS * 64];// LDS weight zone

    // zero xh once: covers pad rows 8..15 and pad cols 400..415 (and h-cols for t=0)
    for (int i = tid; i < 832; i += 256)
        ((uint4*)xh)[i] = make_uint4(0u, 0u, 0u, 0u);

    const bool actj = tid < H;
    float cs[B];
    float bs[4];
    if (actj) {
#pragma unroll
        for (int g = 0; g < 4; ++g)
            bs[g] = bih[(size_t)l * G + g * H + tid] + bhh[(size_t)l * G + g * H + tid];
#pragma unroll
        for (int b = 0; b < B; ++b) cs[b] = 0.0f;
    }

    const uint4* wq = Wm + (size_t)(l * 4 + wv) * NFRAG * 64;

    uint4 wreg[F_REG];
    uint4 s0[NT], s1[NT];
    if (FAST) {
#pragma unroll
        for (int f = 0; f < F_REG; ++f) wreg[f] = wq[f * 64 + lane];
        for (int i = 0; i < F_LDS; ++i)
            wlds[(wv * F_LDS + i) * 64 + lane] = wq[(F_REG + i) * 64 + lane];
        // prologue of the modular stream ring: kt7, kt8
#pragma unroll
        for (int n = 0; n < NT; ++n) s0[n] = wq[(F_REG + F_LDS + 0 * NT + n) * 64 + lane];
#pragma unroll
        for (int n = 0; n < NT; ++n) s1[n] = wq[(F_REG + F_LDS + 1 * NT + n) * 64 + lane];
    }
    float* xhf = (float*)wlds;   // fallback-only f32 view [b*416 + col]
    __syncthreads();

#define LDA(kt) (*(const half8*)&xh[(lane & 15) * 416 + (kt) * 32 + (lane >> 4) * 8])

    for (int t = 0; t < T; ++t) {
        if (FAST) {
            f32x4 acc[NT];
#pragma unroll
            for (int nt = 0; nt < NT; ++nt) acc[nt] = (f32x4){0.f, 0.f, 0.f, 0.f};

#define STREAM_STEP(kt, S, RKT)                                                 \
            do {                                                                \
                half8 a = LDA(kt);                                              \
                _Pragma("unroll")                                               \
                for (int nt = 0; nt < NT; ++nt)                                 \
                    acc[nt] = MFMA16(a, __builtin_bit_cast(half8, S[nt]), acc[nt]); \
                _Pragma("unroll")                                               \
                for (int n = 0; n < NT; ++n)                                    \
                    S[n] = wq[(F_REG + F_LDS + ((RKT) - 7) * NT + n) * 64 + lane]; \
            } while (0)

            // ---- h-part: kt 7..12, uses own h_{t-1} (LDS cols 224..415) ----
            // Runs while the producer is still finishing step t.
            STREAM_STEP(7,  s0, 9);
            STREAM_STEP(8,  s1, 10);
            STREAM_STEP(9,  s0, 11);
            STREAM_STEP(10, s1, 12);
            STREAM_STEP(11, s0, 7);    // prefetch NEXT iteration's kt7
            STREAM_STEP(12, s1, 8);    // prefetch NEXT iteration's kt8
#undef STREAM_STEP

            // ---- wait for producer / ring backpressure (all threads poll) ----
            if (l > 0) {
                const uint32_t need = (uint32_t)(t + 1);
                while (ld_flag(&flags[PFLAG(l - 1)]) < need) __builtin_amdgcn_s_sleep(1);
            }
            if (l < L - 1 && t >= R) {
                const uint32_t need = (uint32_t)(t - R + 1);
                while (ld_flag(&flags[CFLAG(l + 1)]) < need) __builtin_amdgcn_s_sleep(1);
            }

            // ---- stage x_t: ring [j][b] f16 -> LDS xh[b][j], 2 u64 loads/thread ----
            if (actj) {
                u64t p0, p1;
                if (l == 0) {
                    const u64t* s = (const u64t*)h0h + ((size_t)t * H + tid) * 2;
                    p0 = s[0]; p1 = s[1];
                } else {
                    const u64t* s = ring + ((size_t)(l - 1) * R + (t & rmask)) * 400
                                    + (size_t)tid * 2;
                    p0 = ld_u64(s); p1 = ld_u64(s + 1);
                }
#pragma unroll
                for (int b = 0; b < 4; ++b) {
                    xh[b * 416 + tid]       = __builtin_bit_cast(_Float16, (uint16_t)(p0 >> (16 * b)));
                    xh[(b + 4) * 416 + tid] = __builtin_bit_cast(_Float16, (uint16_t)(p1 >> (16 * b)));
                }
            }
            __syncthreads();
            if (tid == 0 && l > 0) st_flag(&flags[CFLAG(l)], (uint32_t)(t + 1));

            // ---- x-part: kt 0..4 (registers) ----
#pragma unroll
            for (int kt = 0; kt < 5; ++kt) {
                half8 a = LDA(kt);
#pragma unroll
                for (int nt = 0; nt < NT; ++nt)
                    acc[nt] = MFMA16(a, __builtin_bit_cast(half8, wreg[kt * NT + nt]), acc[nt]);
            }
            // ---- x-part: kt 5..6 (LDS); kt6 mixes x cols 192..199 + own-h 200..223 ----
#pragma unroll
            for (int kt = 5; kt < 7; ++kt) {
                half8 a = LDA(kt);
#pragma unroll
                for (int nt = 0; nt < NT; ++nt) {
                    uint4 w = wlds[(wv * F_LDS + (kt - 5) * NT + nt) * 64 + lane];
                    acc[nt] = MFMA16(a, __builtin_bit_cast(half8, w), acc[nt]);
                }
            }

            // write gate pre-activations: D row m=(lane>>4)*4+reg (batch), col n=lane&15
            if ((lane >> 4) < 2) {
#pragma unroll
                for (int nt = 0; nt < NT; ++nt) {
                    int nj = nt * 16 + (lane & 15);
#pragma unroll
                    for (int r = 0; r < 4; ++r) {
                        int b = (lane >> 4) * 4 + r;
                        zl[(wv * 8 + b) * 208 + nj] = acc[nt][r];
                    }
                }
            }
            __syncthreads();   // z complete; also guards xh h-col overwrite below

            if (actj) {
                u64t p0 = 0ull, p1 = 0ull;
#pragma unroll
                for (int b = 0; b < B; ++b) {
                    float zi = zl[(0 * 8 + b) * 208 + tid] + bs[0];
                    float zf = zl[(1 * 8 + b) * 208 + tid] + bs[1];
                    float zg = zl[(2 * 8 + b) * 208 + tid] + bs[2];
                    float zo = zl[(3 * 8 + b) * 208 + tid] + bs[3];
                    float ig = fsig(zi);
                    float fg = fsig(zf);
                    float gg = ftanh(zg);
                    float og = fsig(zo);
                    float c  = fg * cs[b] + ig * gg;
                    cs[b] = c;
                    float h = og * ftanh(c);
                    _Float16 hh = (_Float16)h;
                    xh[b * 416 + 200 + tid] = hh;
                    u64t u = (u64t)__builtin_bit_cast(uint16_t, hh);
                    if (b < 4) p0 |= u << (16 * b);
                    else       p1 |= u << (16 * (b - 4));
                    if (l == L - 1) finalbuf[((size_t)b * T + t) * H + tid] = h;
                }
                if (l < L - 1) {
                    u64t* dst = ring + ((size_t)l * R + (t & rmask)) * 400 + (size_t)tid * 2;
                    st_u64(dst, p0);
                    st_u64(dst + 1, p1);
                }
            }
            // wave-level: drains the 2 ring stores (stream prefetch long since landed)
            asm volatile("s_waitcnt vmcnt(0)" ::: "memory");
            __syncthreads();
            if (tid == 0 && l < L - 1) st_flag(&flags[PFLAG(l)], (uint32_t)(t + 1));
        } else {
            // ---------------- f32 fallback (slow but correct-enough) ----------------
            if (l > 0) {
                const uint32_t need = (uint32_t)(t + 1);
                while (ld_flag(&flags[PFLAG(l - 1)]) < need) __builtin_amdgcn_s_sleep(1);
            }
            if (l < L - 1 && t >= R) {
                const uint32_t need = (uint32_t)(t - R + 1);
                while (ld_flag(&flags[CFLAG(l + 1)]) < need) __builtin_amdgcn_s_sleep(1);
            }
            if (actj) {
                u64t p0, p1;
                if (l == 0) {
                    const u64t* s = (const u64t*)h0h + ((size_t)t * H + tid) * 2;
                    p0 = s[0]; p1 = s[1];
                } else {
                    const u64t* s = ring + ((size_t)(l - 1) * R + (t & rmask)) * 400
                                    + (size_t)tid * 2;
                    p0 = ld_u64(s); p1 = ld_u64(s + 1);
                }
#pragma unroll
                for (int b = 0; b < 4; ++b) {
                    xhf[b * 416 + tid]       = (float)__builtin_bit_cast(_Float16, (uint16_t)(p0 >> (16 * b)));
                    xhf[(b + 4) * 416 + tid] = (float)__builtin_bit_cast(_Float16, (uint16_t)(p1 >> (16 * b)));
                }
            }
            __syncthreads();
            if (tid == 0 && l > 0) st_flag(&flags[CFLAG(l)], (uint32_t)(t + 1));

            if (actj) {
                const float* wi0 = Wih + (size_t)l * G * H;
                const float* wh0 = Whh + (size_t)l * G * H;
                float acc[4][B];
#pragma unroll
                for (int g = 0; g < 4; ++g)
#pragma unroll
                    for (int b = 0; b < B; ++b) acc[g][b] = 0.0f;
                for (int k2 = 0; k2 < 200; ++k2) {
                    float2 wvv[4];
                    if (k2 < 100) {
#pragma unroll
                        for (int g = 0; g < 4; ++g)
                            wvv[g] = *(const float2*)&wi0[((size_t)(g * 200 + tid)) * 200 + 2 * k2];
                    } else {
#pragma unroll
                        for (int g = 0; g < 4; ++g)
                            wvv[g] = *(const float2*)&wh0[((size_t)(g * 200 + tid)) * 200 + 2 * (k2 - 100)];
                    }
#pragma unroll
                    for (int b = 0; b < B; ++b) {
                        float2 xv = *(const float2*)&xhf[b * 416 + 2 * k2];
#pragma unroll
                        for (int g = 0; g < 4; ++g) {
                            acc[g][b] += wvv[g].x * xv.x;
                            acc[g][b] += wvv[g].y * xv.y;
                        }
                    }
                }
#pragma unroll
                for (int g = 0; g < 4; ++g)
#pragma unroll
                    for (int b = 0; b < B; ++b)
                        zl[(g * 8 + b) * 208 + tid] = acc[g][b];
            }
            __syncthreads();

            if (actj) {
                u64t p0 = 0ull, p1 = 0ull;
#pragma unroll
                for (int b = 0; b < B; ++b) {
                    float zi = zl[(0 * 8 + b) * 208 + tid] + bs[0];
                    float zf = zl[(1 * 8 + b) * 208 + tid] + bs[1];
                    float zg = zl[(2 * 8 + b) * 208 + tid] + bs[2];
                    float zo = zl[(3 * 8 + b) * 208 + tid] + bs[3];
                    float ig = fsig(zi);
                    float fg = fsig(zf);
                    float gg = ftanh(zg);
                    float og = fsig(zo);
                    float c  = fg * cs[b] + ig * gg;
                    cs[b] = c;
                    float h = og * ftanh(c);
                    xhf[b * 416 + 200 + tid] = h;
                    _Float16 hh = (_Float16)h;
                    u64t u = (u64t)__builtin_bit_cast(uint16_t, hh);
                    if (b < 4) p0 |= u << (16 * b);
                    else       p1 |= u << (16 * (b - 4));
                    if (l == L - 1) finalbuf[((size_t)b * T + t) * H + tid] = h;
                }
                if (l < L - 1) {
                    u64t* dst = ring + ((size_t)l * R + (t & rmask)) * 400 + (size_t)tid * 2;
                    st_u64(dst, p0);
                    st_u64(dst + 1, p1);
                }
            }
            asm volatile("s_waitcnt vmcnt(0)" ::: "memory");
            __syncthreads();
            if (tid == 0 && l < L - 1) st_flag(&flags[PFLAG(l)], (uint32_t)(t + 1));
        }
    }
#undef LDA
}

__global__ __launch_bounds__(64)
void mlp2_kernel(const float* __restrict__ fin, const float* __restrict__ W2a,
                 const float* __restrict__ b2a, const float* __restrict__ W2b,
                 const float* __restrict__ b2b, float* __restrict__ out) {
    const int bt  = blockIdx.x;   // b*T + t
    const int tid = threadIdx.x;
    __shared__ float sx[H];
    __shared__ float sh[50];
    for (int i = tid; i < H; i += 64) sx[i] = fin[(size_t)bt * H + i];
    __syncthreads();
    if (tid < 50) {
        float a = b2a[tid];
        const float* w = W2a + (size_t)tid * H;
        for (int k = 0; k < H; ++k) a += w[k] * sx[k];
        sh[tid] = fmaxf(a, 0.0f);
    }
    __syncthreads();
    if (tid < 24) {
        float a = b2b[tid];
        const float* w = W2b + (size_t)tid * 50;
#pragma unroll
        for (int m = 0; m < 50; ++m) a += w[m] * sh[m];
        out[(size_t)bt * 24 + tid] = a;
    }
}

extern "C" void kernel_launch(void* const* d_in, const int* in_sizes, int n_in,
                              void* d_out, int out_size, void* d_ws, size_t ws_size,
                              hipStream_t stream) {
    const float* x    = (const float*)d_in[0];
    const float* W1   = (const float*)d_in[1];
    const float* b1   = (const float*)d_in[2];
    const float* Wih  = (const float*)d_in[3];
    const float* Whh  = (const float*)d_in[4];
    const float* bihp = (const float*)d_in[5];
    const float* bhhp = (const float*)d_in[6];
    const float* W2a  = (const float*)d_in[7];
    const float* b2a  = (const float*)d_in[8];
    const float* W2b  = (const float*)d_in[9];
    const float* b2b  = (const float*)d_in[10];
    float* out = (float*)d_out;
    float* ws  = (float*)d_ws;

    const size_t wm_halves = (size_t)L * 4 * NFRAG * 64 * 8;   // 69.2M f16
    const size_t wm_u32    = wm_halves / 2;                    // 138.4 MB
    const size_t ring_floats_per_R = (size_t)(L - 1) * B * H / 2;  // f16 ring, per R unit

    int R = 8; bool fast = false; size_t offwm = 0;
    for (;;) {
        size_t o = (OFF_RING + (size_t)R * ring_floats_per_R + 3) & ~(size_t)3;  // 16B align
        if ((o + wm_u32) * 4ull <= ws_size) { fast = true; offwm = o; break; }
        if (R == 1) break;
        R >>= 1;
    }
    if (!fast) {
        R = 8;
        while (R > 1 && (OFF_RING + (size_t)R * ring_floats_per_R) * 4ull > ws_size)
            R >>= 1;
    }
    uint4* Wm = (uint4*)(ws + offwm);

    init_flags<<<32, 256, 0, stream>>>((uint32_t*)d_ws);
    mlp1_kernel<<<(B * T * H + 255) / 256, 256, 0, stream>>>(x, W1, b1,
                                                             (uint16_t*)(ws + OFF_H0));
    if (fast) {
        convert_weights_mfma<<<(int)((wm_halves + 255) / 256), 256, 0, stream>>>(
            Wih, Whh, (uint16_t*)Wm);
        lstm_pipeline<true><<<L, 256, 0, stream>>>(Wm, Wih, Whh, bihp, bhhp, ws, R);
    } else {
        lstm_pipeline<false><<<L, 256, 0, stream>>>(Wm, Wih, Whh, bihp, bhhp, ws, R);
    }
    mlp2_kernel<<<B * T, 64, 0, stream>>>(ws + OFF_FINAL, W2a, b2a, W2b, b2b, out);
}

// Round 2
// 4459.304 us; speedup vs baseline: 1.8056x; 1.8056x over previous
//
#include <hip/hip_runtime.h>
#include <hip/hip_bf16.h>
#include <stdint.h>

#define B 8
#define T 256
#define DIN 6
#define H 200
#define G 800   // 4*H, ifgo gate order
#define L 200

#define NT 13       // N tiles per gate (208 rows, 200 real)
#define KT 13       // K tiles (416 cols, 400 real)
#define NFRAG 169   // NT*KT fragments per (layer,gate)
#define F_REG 65    // kt 0..4  -> registers, f16 (x-part)
#define F_LDS 26    // kt 5..6  -> LDS resident, f16 (x-part + h[0..23])
#define F16F  91    // f16 frags per gate (kt 0..6)
#define F8F   78    // fp8 frags per gate (kt 7..12, streamed h-part)

// ws layout (float/uint32 elements):
#define OFF_H0    8192                       // h0 as f16 [t][j][b]: B*T*H halves
#define OFF_FINAL (OFF_H0 + (B*T*H)/2)       // final as f32 [b][t][j]
#define OFF_RING  (OFF_FINAL + B*T*H)        // ring as f16 [slot][j][b]
#define PFLAG(l)  ((l) * 16)
#define CFLAG(l)  (4096 + (l) * 16)

typedef _Float16 half8 __attribute__((ext_vector_type(8)));
typedef float f32x4 __attribute__((ext_vector_type(4)));
typedef unsigned long long u64t;

__device__ __forceinline__ float fsig(float x) {
    return 1.0f / (1.0f + __expf(-x));
}
__device__ __forceinline__ float ftanh(float x) {
    float e = __expf(2.0f * x);
    return 1.0f - 2.0f / (e + 1.0f);
}

__device__ __forceinline__ uint32_t ld_flag(const uint32_t* p) {
    return __hip_atomic_load(p, __ATOMIC_RELAXED, __HIP_MEMORY_SCOPE_AGENT);
}
__device__ __forceinline__ void st_flag(uint32_t* p, uint32_t v) {
    __hip_atomic_store(p, v, __ATOMIC_RELAXED, __HIP_MEMORY_SCOPE_AGENT);
}
__device__ __forceinline__ u64t ld_u64(const u64t* p) {
    return __hip_atomic_load(p, __ATOMIC_RELAXED, __HIP_MEMORY_SCOPE_AGENT);
}
__device__ __forceinline__ void st_u64(u64t* p, u64t v) {
    __hip_atomic_store(p, v, __ATOMIC_RELAXED, __HIP_MEMORY_SCOPE_AGENT);
}

__global__ void init_flags(uint32_t* ws) {
    int i = blockIdx.x * 256 + threadIdx.x;
    if (i < 8192) ws[i] = 0u;
}

// mlp1: h0 written as f16 in [t][j][b] layout (ring-compatible for l==0 staging)
__global__ void mlp1_kernel(const float* __restrict__ x, const float* __restrict__ W1,
                            const float* __restrict__ b1, uint16_t* __restrict__ h0h) {
    int idx = blockIdx.x * 256 + threadIdx.x;
    if (idx >= B * T * H) return;
    int j  = idx % H;
    int bt = idx / H;          // bt = b*T + t
    int b  = bt / T;
    int t  = bt % T;
    const float* xr = x  + (size_t)bt * DIN;
    const float* wr = W1 + (size_t)j * DIN;
    float a = b1[j];
#pragma unroll
    for (int k = 0; k < DIN; ++k) a += xr[k] * wr[k];
    _Float16 h = (_Float16)a;
    h0h[((size_t)t * H + j) * B + b] = __builtin_bit_cast(uint16_t, h);
}

// One thread per (l, g, frag, lane); writes 8 elements.
// kt<7  -> Wm16 (f16, uint4/lane), fragment id kt*13+nt
// kt>=7 -> Wm8  (fp8 e4m3, u64/lane), fragment id (kt-7)*13+nt
// element j: r = g*200 + nt*16 + (lane&15), k = kt*32 + (lane>>4)*8 + j
__global__ void convert_weights_mfma(const float* __restrict__ Wih,
                                     const float* __restrict__ Whh,
                                     uint4* __restrict__ Wm16,
                                     u64t* __restrict__ Wm8) {
    size_t idx = (size_t)blockIdx.x * 256 + threadIdx.x;
    const size_t TOT = (size_t)L * 4 * NFRAG * 64;
    if (idx >= TOT) return;
    int lane = (int)(idx & 63);
    size_t r0 = idx >> 6;
    int f = (int)(r0 % NFRAG); r0 /= NFRAG;
    int g = (int)(r0 % 4);
    int l = (int)(r0 / 4);
    int kt = f / 13, nt = f % 13;
    int rl = nt * 16 + (lane & 15);
    int r  = g * 200 + rl;
    float v[8];
#pragma unroll
    for (int j = 0; j < 8; ++j) {
        int k = kt * 32 + (lane >> 4) * 8 + j;
        float x = 0.0f;
        if (rl < 200 && k < 400)
            x = (k < 200) ? Wih[((size_t)l * G + r) * 200 + k]
                          : Whh[((size_t)l * G + r) * 200 + (k - 200)];
        v[j] = x;
    }
    if (kt < 7) {
        uint32_t w[4];
#pragma unroll
        for (int p = 0; p < 4; ++p) {
            uint16_t a = __builtin_bit_cast(uint16_t, (_Float16)v[2 * p]);
            uint16_t b = __builtin_bit_cast(uint16_t, (_Float16)v[2 * p + 1]);
            w[p] = (uint32_t)a | ((uint32_t)b << 16);
        }
        Wm16[((size_t)(l * 4 + g) * F16F + f) * 64 + lane] =
            make_uint4(w[0], w[1], w[2], w[3]);
    } else {
        uint32_t lo = __builtin_amdgcn_cvt_pk_fp8_f32(v[0], v[1], 0u, false);
        lo = __builtin_amdgcn_cvt_pk_fp8_f32(v[2], v[3], lo, true);
        uint32_t hi = __builtin_amdgcn_cvt_pk_fp8_f32(v[4], v[5], 0u, false);
        hi = __builtin_amdgcn_cvt_pk_fp8_f32(v[6], v[7], hi, true);
        u64t q = (u64t)lo | ((u64t)hi << 32);
        Wm8[((size_t)(l * 4 + g) * F8F + (kt - 7) * 13 + nt) * 64 + lane] = q;
    }
}

#define MFMA16(a, b, c) __builtin_amdgcn_mfma_f32_16x16x32_f16((a), (b), (c), 0, 0, 0)
#define MFMA8(a, b, c)  __builtin_amdgcn_mfma_f32_16x16x32_fp8_fp8((a), (b), (c), 0, 0, 0)

// One workgroup per layer, 256 threads = 4 waves, wave w = gate w.
// Per step: fp8 h-part GEMM (streamed kt7..12, overlaps producer wait) ->
// flag poll -> f16 u64 stage -> f16 x-part GEMM (reg kt0..4 + LDS kt5..6)
// -> zl exchange -> activation (writes f16 h-cols + fp8 xh8) -> packed ring store -> flag.
template <bool FAST>
__global__ __launch_bounds__(256, 1)
void lstm_pipeline(const uint4* __restrict__ Wm16, const u64t* __restrict__ Wm8,
                   const float* __restrict__ Wih, const float* __restrict__ Whh,
                   const float* __restrict__ bih, const float* __restrict__ bhh,
                   float* ws, int R) {
#pragma clang fp contract(fast)
    const int l     = blockIdx.x;
    const int tid   = threadIdx.x;
    const int wv    = tid >> 6;      // gate index
    const int lane  = tid & 63;
    const int rmask = R - 1;         // R is a power of two

    const uint16_t* h0h = (const uint16_t*)(ws + OFF_H0);
    float*    finalbuf = ws + OFF_FINAL;
    u64t*     ring     = (u64t*)(ws + OFF_RING);   // [slot][j][b] f16, 400 u64/slot
    uint32_t* flags    = (uint32_t*)ws;

    __shared__ __align__(16) _Float16 xh[16 * 416];        // [m][k] f16 A, kt 0..6
    __shared__ __align__(16) uint8_t  xh8[16 * 232];       // [m][c] fp8 A, kt 7..12 (c=k-224)
    __shared__ __align__(16) float    zl[4 * 8 * 208];     // [g][b][nj]
    __shared__ __align__(16) uint4    wlds[4 * F_LDS * 64];// f16 LDS weight zone

    // zero once: xh pad rows/cols, xh8 pad rows 8..15 and cols 176..223 (h_{-1}=0 too)
    for (int i = tid; i < 832; i += 256)
        ((uint4*)xh)[i] = make_uint4(0u, 0u, 0u, 0u);
    for (int i = tid; i < 232; i += 256)
        ((uint4*)xh8)[i] = make_uint4(0u, 0u, 0u, 0u);

    const bool actj = tid < H;
    float cs[B];
    float bs[4];
    if (actj) {
#pragma unroll
        for (int g = 0; g < 4; ++g)
            bs[g] = bih[(size_t)l * G + g * H + tid] + bhh[(size_t)l * G + g * H + tid];
#pragma unroll
        for (int b = 0; b < B; ++b) cs[b] = 0.0f;
    }

    const uint4* wq16 = Wm16 + (size_t)(l * 4 + wv) * F16F * 64;
    const u64t*  wq8  = Wm8  + (size_t)(l * 4 + wv) * F8F * 64;

    uint4 wreg[F_REG];
    u64t sA[13], sB[13], sC[13];
    if (FAST) {
#pragma unroll
        for (int f = 0; f < F_REG; ++f) wreg[f] = wq16[f * 64 + lane];
        for (int i = 0; i < F_LDS; ++i)
            wlds[(wv * F_LDS + i) * 64 + lane] = wq16[(F_REG + i) * 64 + lane];
        // prologue of the 3-deep stream ring: blocks 0,1,2 = kt 7,8,9
#pragma unroll
        for (int n = 0; n < 13; ++n) sA[n] = wq8[(0 * 13 + n) * 64 + lane];
#pragma unroll
        for (int n = 0; n < 13; ++n) sB[n] = wq8[(1 * 13 + n) * 64 + lane];
#pragma unroll
        for (int n = 0; n < 13; ++n) sC[n] = wq8[(2 * 13 + n) * 64 + lane];
    }
    float* xhf = (float*)wlds;   // fallback-only f32 view [b*416 + col]
    __syncthreads();

#define LDA(kt)  (*(const half8*)&xh[(lane & 15) * 416 + (kt) * 32 + (lane >> 4) * 8])
#define LDA8(kt) (*(const long*)&xh8[(lane & 15) * 232 + ((kt) - 7) * 32 + (lane >> 4) * 8])

    for (int t = 0; t < T; ++t) {
        if (FAST) {
            f32x4 acc[NT];
#pragma unroll
            for (int nt = 0; nt < NT; ++nt) acc[nt] = (f32x4){0.f, 0.f, 0.f, 0.f};

#define STREAM8(kt, S, RF)                                                      \
            do {                                                                \
                long a = LDA8(kt);                                              \
                _Pragma("unroll")                                               \
                for (int nt = 0; nt < NT; ++nt)                                 \
                    acc[nt] = MFMA8(a, (long)S[nt], acc[nt]);                   \
                _Pragma("unroll")                                               \
                for (int n = 0; n < 13; ++n)                                    \
                    S[n] = wq8[((RF) * 13 + n) * 64 + lane];                    \
            } while (0)

            // ---- h-part (fp8): kt 7..12, uses own h_{t-1}; overlaps producer wait ----
            STREAM8(7,  sA, 3);   // refill kt10
            STREAM8(8,  sB, 4);   // refill kt11
            STREAM8(9,  sC, 5);   // refill kt12
            STREAM8(10, sA, 0);   // refill next step's kt7
            STREAM8(11, sB, 1);   // refill next step's kt8
            STREAM8(12, sC, 2);   // refill next step's kt9
#undef STREAM8

            // ---- wait for producer / ring backpressure ----
            if (l > 0) {
                const uint32_t need = (uint32_t)(t + 1);
                while (ld_flag(&flags[PFLAG(l - 1)]) < need) __builtin_amdgcn_s_sleep(1);
            }
            if (l < L - 1 && t >= R) {
                const uint32_t need = (uint32_t)(t - R + 1);
                while (ld_flag(&flags[CFLAG(l + 1)]) < need) __builtin_amdgcn_s_sleep(1);
            }

            // ---- stage x_t: ring [j][b] f16 -> LDS xh[b][j], 2 u64 loads/thread ----
            if (actj) {
                u64t p0, p1;
                if (l == 0) {
                    const u64t* s = (const u64t*)h0h + ((size_t)t * H + tid) * 2;
                    p0 = s[0]; p1 = s[1];
                } else {
                    const u64t* s = ring + ((size_t)(l - 1) * R + (t & rmask)) * 400
                                    + (size_t)tid * 2;
                    p0 = ld_u64(s); p1 = ld_u64(s + 1);
                }
#pragma unroll
                for (int b = 0; b < 4; ++b) {
                    xh[b * 416 + tid]       = __builtin_bit_cast(_Float16, (uint16_t)(p0 >> (16 * b)));
                    xh[(b + 4) * 416 + tid] = __builtin_bit_cast(_Float16, (uint16_t)(p1 >> (16 * b)));
                }
            }
            __syncthreads();
            if (tid == 0 && l > 0) st_flag(&flags[CFLAG(l)], (uint32_t)(t + 1));

            // ---- x-part (f16): kt 0..4 registers ----
#pragma unroll
            for (int kt = 0; kt < 5; ++kt) {
                half8 a = LDA(kt);
#pragma unroll
                for (int nt = 0; nt < NT; ++nt)
                    acc[nt] = MFMA16(a, __builtin_bit_cast(half8, wreg[kt * NT + nt]), acc[nt]);
            }
            // ---- x-part (f16): kt 5..6 LDS; kt6 = x cols 192..199 + own-h 200..223 ----
#pragma unroll
            for (int kt = 5; kt < 7; ++kt) {
                half8 a = LDA(kt);
#pragma unroll
                for (int nt = 0; nt < NT; ++nt) {
                    uint4 w = wlds[(wv * F_LDS + (kt - 5) * NT + nt) * 64 + lane];
                    acc[nt] = MFMA16(a, __builtin_bit_cast(half8, w), acc[nt]);
                }
            }

            // write gate pre-activations: D row m=(lane>>4)*4+reg (batch), col n=lane&15
            if ((lane >> 4) < 2) {
#pragma unroll
                for (int nt = 0; nt < NT; ++nt) {
                    int nj = nt * 16 + (lane & 15);
#pragma unroll
                    for (int r = 0; r < 4; ++r) {
                        int b = (lane >> 4) * 4 + r;
                        zl[(wv * 8 + b) * 208 + nj] = acc[nt][r];
                    }
                }
            }
            __syncthreads();   // z complete; also guards xh/xh8 h overwrite below

            if (actj) {
                u64t p0 = 0ull, p1 = 0ull;
#pragma unroll
                for (int b = 0; b < B; ++b) {
                    float zi = zl[(0 * 8 + b) * 208 + tid] + bs[0];
                    float zf = zl[(1 * 8 + b) * 208 + tid] + bs[1];
                    float zg = zl[(2 * 8 + b) * 208 + tid] + bs[2];
                    float zo = zl[(3 * 8 + b) * 208 + tid] + bs[3];
                    float ig = fsig(zi);
                    float fg = fsig(zf);
                    float gg = ftanh(zg);
                    float og = fsig(zo);
                    float c  = fg * cs[b] + ig * gg;
                    cs[b] = c;
                    float h = og * ftanh(c);
                    _Float16 hh = (_Float16)h;
                    xh[b * 416 + 200 + tid] = hh;
                    if (tid >= 24) {
                        uint32_t f8 = __builtin_amdgcn_cvt_pk_fp8_f32(h, h, 0u, false);
                        xh8[b * 232 + (tid - 24)] = (uint8_t)(f8 & 0xffu);
                    }
                    u64t u = (u64t)__builtin_bit_cast(uint16_t, hh);
                    if (b < 4) p0 |= u << (16 * b);
                    else       p1 |= u << (16 * (b - 4));
                    if (l == L - 1) finalbuf[((size_t)b * T + t) * H + tid] = h;
                }
                if (l < L - 1) {
                    u64t* dst = ring + ((size_t)l * R + (t & rmask)) * 400 + (size_t)tid * 2;
                    st_u64(dst, p0);
                    st_u64(dst + 1, p1);
                }
            }
            // drains ring stores (stream prefetches are loads, long since landed)
            asm volatile("s_waitcnt vmcnt(0)" ::: "memory");
            __syncthreads();
            if (tid == 0 && l < L - 1) st_flag(&flags[PFLAG(l)], (uint32_t)(t + 1));
        } else {
            // ---------------- f32 fallback (slow but correct-enough) ----------------
            if (l > 0) {
                const uint32_t need = (uint32_t)(t + 1);
                while (ld_flag(&flags[PFLAG(l - 1)]) < need) __builtin_amdgcn_s_sleep(1);
            }
            if (l < L - 1 && t >= R) {
                const uint32_t need = (uint32_t)(t - R + 1);
                while (ld_flag(&flags[CFLAG(l + 1)]) < need) __builtin_amdgcn_s_sleep(1);
            }
            if (actj) {
                u64t p0, p1;
                if (l == 0) {
                    const u64t* s = (const u64t*)h0h + ((size_t)t * H + tid) * 2;
                    p0 = s[0]; p1 = s[1];
                } else {
                    const u64t* s = ring + ((size_t)(l - 1) * R + (t & rmask)) * 400
                                    + (size_t)tid * 2;
                    p0 = ld_u64(s); p1 = ld_u64(s + 1);
                }
#pragma unroll
                for (int b = 0; b < 4; ++b) {
                    xhf[b * 416 + tid]       = (float)__builtin_bit_cast(_Float16, (uint16_t)(p0 >> (16 * b)));
                    xhf[(b + 4) * 416 + tid] = (float)__builtin_bit_cast(_Float16, (uint16_t)(p1 >> (16 * b)));
                }
            }
            __syncthreads();
            if (tid == 0 && l > 0) st_flag(&flags[CFLAG(l)], (uint32_t)(t + 1));

            if (actj) {
                const float* wi0 = Wih + (size_t)l * G * H;
                const float* wh0 = Whh + (size_t)l * G * H;
                float acc[4][B];
#pragma unroll
                for (int g = 0; g < 4; ++g)
#pragma unroll
                    for (int b = 0; b < B; ++b) acc[g][b] = 0.0f;
                for (int k2 = 0; k2 < 200; ++k2) {
                    float2 wvv[4];
                    if (k2 < 100) {
#pragma unroll
                        for (int g = 0; g < 4; ++g)
                            wvv[g] = *(const float2*)&wi0[((size_t)(g * 200 + tid)) * 200 + 2 * k2];
                    } else {
#pragma unroll
                        for (int g = 0; g < 4; ++g)
                            wvv[g] = *(const float2*)&wh0[((size_t)(g * 200 + tid)) * 200 + 2 * (k2 - 100)];
                    }
#pragma unroll
                    for (int b = 0; b < B; ++b) {
                        float2 xv = *(const float2*)&xhf[b * 416 + 2 * k2];
#pragma unroll
                        for (int g = 0; g < 4; ++g) {
                            acc[g][b] += wvv[g].x * xv.x;
                            acc[g][b] += wvv[g].y * xv.y;
                        }
                    }
                }
#pragma unroll
                for (int g = 0; g < 4; ++g)
#pragma unroll
                    for (int b = 0; b < B; ++b)
                        zl[(g * 8 + b) * 208 + tid] = acc[g][b];
            }
            __syncthreads();

            if (actj) {
                u64t p0 = 0ull, p1 = 0ull;
#pragma unroll
                for (int b = 0; b < B; ++b) {
                    float zi = zl[(0 * 8 + b) * 208 + tid] + bs[0];
                    float zf = zl[(1 * 8 + b) * 208 + tid] + bs[1];
                    float zg = zl[(2 * 8 + b) * 208 + tid] + bs[2];
                    float zo = zl[(3 * 8 + b) * 208 + tid] + bs[3];
                    float ig = fsig(zi);
                    float fg = fsig(zf);
                    float gg = ftanh(zg);
                    float og = fsig(zo);
                    float c  = fg * cs[b] + ig * gg;
                    cs[b] = c;
                    float h = og * ftanh(c);
                    xhf[b * 416 + 200 + tid] = h;
                    _Float16 hh = (_Float16)h;
                    u64t u = (u64t)__builtin_bit_cast(uint16_t, hh);
                    if (b < 4) p0 |= u << (16 * b);
                    else       p1 |= u << (16 * (b - 4));
                    if (l == L - 1) finalbuf[((size_t)b * T + t) * H + tid] = h;
                }
                if (l < L - 1) {
                    u64t* dst = ring + ((size_t)l * R + (t & rmask)) * 400 + (size_t)tid * 2;
                    st_u64(dst, p0);
                    st_u64(dst + 1, p1);
                }
            }
            asm volatile("s_waitcnt vmcnt(0)" ::: "memory");
            __syncthreads();
            if (tid == 0 && l < L - 1) st_flag(&flags[PFLAG(l)], (uint32_t)(t + 1));
        }
    }
#undef LDA
#undef LDA8
}

__global__ __launch_bounds__(64)
void mlp2_kernel(const float* __restrict__ fin, const float* __restrict__ W2a,
                 const float* __restrict__ b2a, const float* __restrict__ W2b,
                 const float* __restrict__ b2b, float* __restrict__ out) {
    const int bt  = blockIdx.x;   // b*T + t
    const int tid = threadIdx.x;
    __shared__ float sx[H];
    __shared__ float sh[50];
    for (int i = tid; i < H; i += 64) sx[i] = fin[(size_t)bt * H + i];
    __syncthreads();
    if (tid < 50) {
        float a = b2a[tid];
        const float* w = W2a + (size_t)tid * H;
        for (int k = 0; k < H; ++k) a += w[k] * sx[k];
        sh[tid] = fmaxf(a, 0.0f);
    }
    __syncthreads();
    if (tid < 24) {
        float a = b2b[tid];
        const float* w = W2b + (size_t)tid * 50;
#pragma unroll
        for (int m = 0; m < 50; ++m) a += w[m] * sh[m];
        out[(size_t)bt * 24 + tid] = a;
    }
}

extern "C" void kernel_launch(void* const* d_in, const int* in_sizes, int n_in,
                              void* d_out, int out_size, void* d_ws, size_t ws_size,
                              hipStream_t stream) {
    const float* x    = (const float*)d_in[0];
    const float* W1   = (const float*)d_in[1];
    const float* b1   = (const float*)d_in[2];
    const float* Wih  = (const float*)d_in[3];
    const float* Whh  = (const float*)d_in[4];
    const float* bihp = (const float*)d_in[5];
    const float* bhhp = (const float*)d_in[6];
    const float* W2a  = (const float*)d_in[7];
    const float* b2a  = (const float*)d_in[8];
    const float* W2b  = (const float*)d_in[9];
    const float* b2b  = (const float*)d_in[10];
    float* out = (float*)d_out;
    float* ws  = (float*)d_ws;

    // f16 zone: L*4*91 frags * 64 lanes * 16 B ; fp8 zone: L*4*78 * 64 * 8 B
    const size_t wm16_u32 = (size_t)L * 4 * F16F * 64 * 4;   // 18.64M u32 = 74.5 MB
    const size_t wm8_u32  = (size_t)L * 4 * F8F  * 64 * 2;   //  7.99M u32 = 32.0 MB
    const size_t ring_u32_per_R = (size_t)(L - 1) * B * H / 2;  // f16 ring per R unit

    int R = 8; bool fast = false; size_t offwm = 0;
    for (;;) {
        size_t o = (OFF_RING + (size_t)R * ring_u32_per_R + 3) & ~(size_t)3;  // 16B align
        if ((o + wm16_u32 + wm8_u32) * 4ull <= ws_size) { fast = true; offwm = o; break; }
        if (R == 1) break;
        R >>= 1;
    }
    if (!fast) {
        R = 8;
        while (R > 1 && (OFF_RING + (size_t)R * ring_u32_per_R) * 4ull > ws_size)
            R >>= 1;
    }
    uint4* Wm16 = (uint4*)(ws + offwm);
    u64t*  Wm8  = (u64t*)(ws + offwm + wm16_u32);

    init_flags<<<32, 256, 0, stream>>>((uint32_t*)d_ws);
    mlp1_kernel<<<(B * T * H + 255) / 256, 256, 0, stream>>>(x, W1, b1,
                                                             (uint16_t*)(ws + OFF_H0));
    if (fast) {
        const size_t conv_threads = (size_t)L * 4 * NFRAG * 64;
        convert_weights_mfma<<<(int)((conv_threads + 255) / 256), 256, 0, stream>>>(
            Wih, Whh, Wm16, Wm8);
        lstm_pipeline<true><<<L, 256, 0, stream>>>(Wm16, Wm8, Wih, Whh, bihp, bhhp, ws, R);
    } else {
        lstm_pipeline<false><<<L, 256, 0, stream>>>(Wm16, Wm8, Wih, Whh, bihp, bhhp, ws, R);
    }
    mlp2_kernel<<<B * T, 64, 0, stream>>>(ws + OFF_FINAL, W2a, b2a, W2b, b2b, out);
}

// Round 3
// 2933.831 us; speedup vs baseline: 2.7445x; 1.5200x over previous
//
#include <hip/hip_runtime.h>
#include <hip/hip_bf16.h>
#include <stdint.h>

#define B 8
#define T 256
#define DIN 6
#define H 200
#define G 800   // 4*H, ifgo gate order
#define L 200

#define NT 13       // N tiles per gate (208 rows, 200 real)
#define KT 13       // K tiles (416 cols, 400 real)
#define NFRAG 169   // NT*KT fragments per (layer,gate), all fp8
#define F_RG 117    // kt 0..8  -> registers (u64/lane each)
#define F_LD 52     // kt 9..12 -> LDS resident
#define XPAD 424    // xh8 row stride (fp8 bytes): 424 = conflict-free for b64 reads

// ws layout (float/uint32 elements):
#define OFF_H0    8192                       // h0 f16 [t][word][j][4b]: B*T*H halves
#define OFF_FINAL (OFF_H0 + (B*T*H)/2)       // final f32 [b][t][j]
#define OFF_RING  (OFF_FINAL + B*T*H)        // ring f16 [slot][word][j][4b]
#define PFLAG(l)  ((l) * 16)
#define CFLAG(l)  (4096 + (l) * 16)

typedef _Float16 half8 __attribute__((ext_vector_type(8)));
typedef float f32x4 __attribute__((ext_vector_type(4)));
typedef unsigned long long u64t;

__device__ __forceinline__ float fsig(float x) {
    return 1.0f / (1.0f + __expf(-x));
}
__device__ __forceinline__ float ftanh(float x) {
    float e = __expf(2.0f * x);
    return 1.0f - 2.0f / (e + 1.0f);
}

__device__ __forceinline__ uint32_t ld_flag(const uint32_t* p) {
    return __hip_atomic_load(p, __ATOMIC_RELAXED, __HIP_MEMORY_SCOPE_AGENT);
}
__device__ __forceinline__ void st_flag(uint32_t* p, uint32_t v) {
    __hip_atomic_store(p, v, __ATOMIC_RELAXED, __HIP_MEMORY_SCOPE_AGENT);
}
__device__ __forceinline__ u64t ld_u64(const u64t* p) {
    return __hip_atomic_load(p, __ATOMIC_RELAXED, __HIP_MEMORY_SCOPE_AGENT);
}
__device__ __forceinline__ void st_u64(u64t* p, u64t v) {
    __hip_atomic_store(p, v, __ATOMIC_RELAXED, __HIP_MEMORY_SCOPE_AGENT);
}
__device__ __forceinline__ uint8_t to_fp8(float v) {
    return (uint8_t)(__builtin_amdgcn_cvt_pk_fp8_f32(v, v, 0u, false) & 0xffu);
}

__global__ void init_flags(uint32_t* ws) {
    int i = blockIdx.x * 256 + threadIdx.x;
    if (i < 8192) ws[i] = 0u;
}

// mlp1: h0 as f16 in [t][word][j][b&3] layout (word = b>>2), ring-compatible.
__global__ void mlp1_kernel(const float* __restrict__ x, const float* __restrict__ W1,
                            const float* __restrict__ b1, uint16_t* __restrict__ h0h) {
    int idx = blockIdx.x * 256 + threadIdx.x;
    if (idx >= B * T * H) return;
    int j  = idx % H;
    int bt = idx / H;          // bt = b*T + t
    int b  = bt / T;
    int t  = bt % T;
    const float* xr = x  + (size_t)bt * DIN;
    const float* wr = W1 + (size_t)j * DIN;
    float a = b1[j];
#pragma unroll
    for (int k = 0; k < DIN; ++k) a += xr[k] * wr[k];
    _Float16 h = (_Float16)a;
    h0h[((size_t)(t * 2 + (b >> 2)) * H + j) * 4 + (b & 3)] = __builtin_bit_cast(uint16_t, h);
}

// All weights fp8 e4m3. One thread per (l, g, frag, lane); writes u64 (8 fp8).
// frag f = kt*13+nt; element j: r = g*200 + nt*16 + (lane&15),
// k = kt*32 + (lane>>4)*8 + j ; Wcat[r][k] = k<200 ? Wih : Whh[k-200]; 0 pad.
__global__ void convert_weights_mfma(const float* __restrict__ Wih,
                                     const float* __restrict__ Whh,
                                     u64t* __restrict__ Wm8) {
    size_t idx = (size_t)blockIdx.x * 256 + threadIdx.x;
    const size_t TOT = (size_t)L * 4 * NFRAG * 64;
    if (idx >= TOT) return;
    int lane = (int)(idx & 63);
    size_t r0 = idx >> 6;
    int f = (int)(r0 % NFRAG); r0 /= NFRAG;
    int g = (int)(r0 % 4);
    int l = (int)(r0 / 4);
    int kt = f / 13, nt = f % 13;
    int rl = nt * 16 + (lane & 15);
    int r  = g * 200 + rl;
    float v[8];
#pragma unroll
    for (int j = 0; j < 8; ++j) {
        int k = kt * 32 + (lane >> 4) * 8 + j;
        float xx = 0.0f;
        if (rl < 200 && k < 400)
            xx = (k < 200) ? Wih[((size_t)l * G + r) * 200 + k]
                           : Whh[((size_t)l * G + r) * 200 + (k - 200)];
        v[j] = xx;
    }
    uint32_t lo = __builtin_amdgcn_cvt_pk_fp8_f32(v[0], v[1], 0u, false);
    lo = __builtin_amdgcn_cvt_pk_fp8_f32(v[2], v[3], lo, true);
    uint32_t hi = __builtin_amdgcn_cvt_pk_fp8_f32(v[4], v[5], 0u, false);
    hi = __builtin_amdgcn_cvt_pk_fp8_f32(v[6], v[7], hi, true);
    Wm8[((size_t)(l * 4 + g) * NFRAG + f) * 64 + lane] = (u64t)lo | ((u64t)hi << 32);
}

#define MFMA8(a, b, c)  __builtin_amdgcn_mfma_f32_16x16x32_fp8_fp8((a), (b), (c), 0, 0, 0)

// One workgroup per layer, 256 threads = 4 waves, wave w = gate w.
// ALL weights resident: kt0..8 in registers (117 u64/lane), kt9..12 in LDS.
// Per step: h-part GEMM (kt7..12, own h_{t-1}; overlaps producer wait) ->
// flag poll -> stage x (f16 ring -> fp8 LDS) -> x-part GEMM (kt0..6) ->
// zl exchange -> activation (fp8 h into xh8) -> dense u64 ring store -> flag.
template <bool FAST>
__global__ __launch_bounds__(256, 1)
void lstm_pipeline(const u64t* __restrict__ Wm8,
                   const float* __restrict__ Wih, const float* __restrict__ Whh,
                   const float* __restrict__ bih, const float* __restrict__ bhh,
                   float* ws, int R) {
#pragma clang fp contract(fast)
    const int l     = blockIdx.x;
    const int tid   = threadIdx.x;
    const int wv    = tid >> 6;      // gate index
    const int lane  = tid & 63;
    const int rmask = R - 1;         // R is a power of two

    const u64t* h0h = (const u64t*)(ws + OFF_H0);
    float*    finalbuf = ws + OFF_FINAL;
    u64t*     ring     = (u64t*)(ws + OFF_RING);   // [slot][word][j][4b] f16, 400 u64/slot
    uint32_t* flags    = (uint32_t*)ws;

    __shared__ __align__(16) uint8_t  xh8[16 * XPAD];      // [m][k] fp8 A, k=0..415 (+pad)
    __shared__ __align__(16) float    zl[4 * 8 * 208];     // [g][b][nj]
    __shared__ __align__(16) u64t     wl8[4 * F_LD * 64];  // fp8 weight zone kt9..12

    // zero xh8 once: pad rows 8..15, pad cols 400.., and h-cols for t=0 (h_{-1}=0)
    for (int i = tid; i < (16 * XPAD) / 16; i += 256)
        ((uint4*)xh8)[i] = make_uint4(0u, 0u, 0u, 0u);

    const bool actj = tid < H;
    float cs[B];
    float bs[4];
    if (actj) {
#pragma unroll
        for (int g = 0; g < 4; ++g)
            bs[g] = bih[(size_t)l * G + g * H + tid] + bhh[(size_t)l * G + g * H + tid];
#pragma unroll
        for (int b = 0; b < B; ++b) cs[b] = 0.0f;
    }

    const u64t* wq8 = Wm8 + (size_t)(l * 4 + wv) * NFRAG * 64;

    u64t wr8[F_RG];
    if (FAST) {
#pragma unroll
        for (int f = 0; f < F_RG; ++f) wr8[f] = wq8[f * 64 + lane];
        for (int i = 0; i < F_LD; ++i)
            wl8[(wv * F_LD + i) * 64 + lane] = wq8[(F_RG + i) * 64 + lane];
    }
    float* xhf = (float*)wl8;   // fallback-only f32 view [b*416 + col]
    __syncthreads();

#define LDA8(kt) (*(const long*)&xh8[(lane & 15) * XPAD + (kt) * 32 + (lane >> 4) * 8])

    for (int t = 0; t < T; ++t) {
        if (FAST) {
            f32x4 acc[NT];
#pragma unroll
            for (int nt = 0; nt < NT; ++nt) acc[nt] = (f32x4){0.f, 0.f, 0.f, 0.f};

            // ---- h-part: kt 7..8 (registers) -- uses own h_{t-1} ----
#pragma unroll
            for (int kt = 7; kt < 9; ++kt) {
                long a = LDA8(kt);
#pragma unroll
                for (int nt = 0; nt < NT; ++nt)
                    acc[nt] = MFMA8(a, (long)wr8[kt * NT + nt], acc[nt]);
            }
            // ---- h-part: kt 9..12 (LDS) ----
#pragma unroll
            for (int kt = 9; kt < 13; ++kt) {
                long a = LDA8(kt);
#pragma unroll
                for (int nt = 0; nt < NT; ++nt) {
                    u64t w = wl8[(wv * F_LD + (kt - 9) * NT + nt) * 64 + lane];
                    acc[nt] = MFMA8(a, (long)w, acc[nt]);
                }
            }

            // ---- wait for producer / ring backpressure (all threads poll) ----
            if (l > 0) {
                const uint32_t need = (uint32_t)(t + 1);
                while (ld_flag(&flags[PFLAG(l - 1)]) < need) __builtin_amdgcn_s_sleep(1);
            }
            if (l < L - 1 && t >= R) {
                const uint32_t need = (uint32_t)(t - R + 1);
                while (ld_flag(&flags[CFLAG(l + 1)]) < need) __builtin_amdgcn_s_sleep(1);
            }

            // ---- stage x_t: f16 [word][j][4b] -> fp8 LDS xh8[b][j] ----
            if (actj) {
                u64t p0, p1;
                if (l == 0) {
                    p0 = h0h[(size_t)(t * 2 + 0) * H + tid];
                    p1 = h0h[(size_t)(t * 2 + 1) * H + tid];
                } else {
                    const u64t* s = ring + ((size_t)(l - 1) * R + (t & rmask)) * 400;
                    p0 = ld_u64(s + tid);
                    p1 = ld_u64(s + 200 + tid);
                }
#pragma unroll
                for (int b = 0; b < 4; ++b) {
                    float f0 = (float)__builtin_bit_cast(_Float16, (uint16_t)(p0 >> (16 * b)));
                    float f1 = (float)__builtin_bit_cast(_Float16, (uint16_t)(p1 >> (16 * b)));
                    xh8[b * XPAD + tid]       = to_fp8(f0);
                    xh8[(b + 4) * XPAD + tid] = to_fp8(f1);
                }
            }
            __syncthreads();
            if (tid == 0 && l > 0) st_flag(&flags[CFLAG(l)], (uint32_t)(t + 1));

            // ---- x-part: kt 0..6 (registers); kt6 = x 192..199 + own-h 200..223 ----
#pragma unroll
            for (int kt = 0; kt < 7; ++kt) {
                long a = LDA8(kt);
#pragma unroll
                for (int nt = 0; nt < NT; ++nt)
                    acc[nt] = MFMA8(a, (long)wr8[kt * NT + nt], acc[nt]);
            }

            // write gate pre-activations: D row m=(lane>>4)*4+reg (batch), col n=lane&15
            if ((lane >> 4) < 2) {
#pragma unroll
                for (int nt = 0; nt < NT; ++nt) {
                    int nj = nt * 16 + (lane & 15);
#pragma unroll
                    for (int r = 0; r < 4; ++r) {
                        int b = (lane >> 4) * 4 + r;
                        zl[(wv * 8 + b) * 208 + nj] = acc[nt][r];
                    }
                }
            }
            __syncthreads();   // z complete; also guards xh8 h-col overwrite below

            if (actj) {
                u64t p0 = 0ull, p1 = 0ull;
#pragma unroll
                for (int b = 0; b < B; ++b) {
                    float zi = zl[(0 * 8 + b) * 208 + tid] + bs[0];
                    float zf = zl[(1 * 8 + b) * 208 + tid] + bs[1];
                    float zg = zl[(2 * 8 + b) * 208 + tid] + bs[2];
                    float zo = zl[(3 * 8 + b) * 208 + tid] + bs[3];
                    float ig = fsig(zi);
                    float fg = fsig(zf);
                    float gg = ftanh(zg);
                    float og = fsig(zo);
                    float c  = fg * cs[b] + ig * gg;
                    cs[b] = c;
                    float h = og * ftanh(c);
                    xh8[b * XPAD + 200 + tid] = to_fp8(h);
                    _Float16 hh = (_Float16)h;
                    u64t u = (u64t)__builtin_bit_cast(uint16_t, hh);
                    if (b < 4) p0 |= u << (16 * b);
                    else       p1 |= u << (16 * (b - 4));
                    if (l == L - 1) finalbuf[((size_t)b * T + t) * H + tid] = h;
                }
                if (l < L - 1) {
                    u64t* dst = ring + ((size_t)l * R + (t & rmask)) * 400;
                    st_u64(dst + tid, p0);          // word 0: dense 200 u64
                    st_u64(dst + 200 + tid, p1);    // word 1: dense 200 u64
                }
            }
            asm volatile("s_waitcnt vmcnt(0)" ::: "memory");
            __syncthreads();
            if (tid == 0 && l < L - 1) st_flag(&flags[PFLAG(l)], (uint32_t)(t + 1));
        } else {
            // ---------------- f32 fallback (slow but correct-enough) ----------------
            if (l > 0) {
                const uint32_t need = (uint32_t)(t + 1);
                while (ld_flag(&flags[PFLAG(l - 1)]) < need) __builtin_amdgcn_s_sleep(1);
            }
            if (l < L - 1 && t >= R) {
                const uint32_t need = (uint32_t)(t - R + 1);
                while (ld_flag(&flags[CFLAG(l + 1)]) < need) __builtin_amdgcn_s_sleep(1);
            }
            if (actj) {
                u64t p0, p1;
                if (l == 0) {
                    p0 = h0h[(size_t)(t * 2 + 0) * H + tid];
                    p1 = h0h[(size_t)(t * 2 + 1) * H + tid];
                } else {
                    const u64t* s = ring + ((size_t)(l - 1) * R + (t & rmask)) * 400;
                    p0 = ld_u64(s + tid);
                    p1 = ld_u64(s + 200 + tid);
                }
#pragma unroll
                for (int b = 0; b < 4; ++b) {
                    xhf[b * 416 + tid]       = (float)__builtin_bit_cast(_Float16, (uint16_t)(p0 >> (16 * b)));
                    xhf[(b + 4) * 416 + tid] = (float)__builtin_bit_cast(_Float16, (uint16_t)(p1 >> (16 * b)));
                }
            }
            __syncthreads();
            if (tid == 0 && l > 0) st_flag(&flags[CFLAG(l)], (uint32_t)(t + 1));

            if (actj) {
                const float* wi0 = Wih + (size_t)l * G * H;
                const float* wh0 = Whh + (size_t)l * G * H;
                float acc[4][B];
#pragma unroll
                for (int g = 0; g < 4; ++g)
#pragma unroll
                    for (int b = 0; b < B; ++b) acc[g][b] = 0.0f;
                for (int k2 = 0; k2 < 200; ++k2) {
                    float2 wvv[4];
                    if (k2 < 100) {
#pragma unroll
                        for (int g = 0; g < 4; ++g)
                            wvv[g] = *(const float2*)&wi0[((size_t)(g * 200 + tid)) * 200 + 2 * k2];
                    } else {
#pragma unroll
                        for (int g = 0; g < 4; ++g)
                            wvv[g] = *(const float2*)&wh0[((size_t)(g * 200 + tid)) * 200 + 2 * (k2 - 100)];
                    }
#pragma unroll
                    for (int b = 0; b < B; ++b) {
                        float2 xv = *(const float2*)&xhf[b * 416 + 2 * k2];
#pragma unroll
                        for (int g = 0; g < 4; ++g) {
                            acc[g][b] += wvv[g].x * xv.x;
                            acc[g][b] += wvv[g].y * xv.y;
                        }
                    }
                }
#pragma unroll
                for (int g = 0; g < 4; ++g)
#pragma unroll
                    for (int b = 0; b < B; ++b)
                        zl[(g * 8 + b) * 208 + tid] = acc[g][b];
            }
            __syncthreads();

            if (actj) {
                u64t p0 = 0ull, p1 = 0ull;
#pragma unroll
                for (int b = 0; b < B; ++b) {
                    float zi = zl[(0 * 8 + b) * 208 + tid] + bs[0];
                    float zf = zl[(1 * 8 + b) * 208 + tid] + bs[1];
                    float zg = zl[(2 * 8 + b) * 208 + tid] + bs[2];
                    float zo = zl[(3 * 8 + b) * 208 + tid] + bs[3];
                    float ig = fsig(zi);
                    float fg = fsig(zf);
                    float gg = ftanh(zg);
                    float og = fsig(zo);
                    float c  = fg * cs[b] + ig * gg;
                    cs[b] = c;
                    float h = og * ftanh(c);
                    xhf[b * 416 + 200 + tid] = h;
                    _Float16 hh = (_Float16)h;
                    u64t u = (u64t)__builtin_bit_cast(uint16_t, hh);
                    if (b < 4) p0 |= u << (16 * b);
                    else       p1 |= u << (16 * (b - 4));
                    if (l == L - 1) finalbuf[((size_t)b * T + t) * H + tid] = h;
                }
                if (l < L - 1) {
                    u64t* dst = ring + ((size_t)l * R + (t & rmask)) * 400;
                    st_u64(dst + tid, p0);
                    st_u64(dst + 200 + tid, p1);
                }
            }
            asm volatile("s_waitcnt vmcnt(0)" ::: "memory");
            __syncthreads();
            if (tid == 0 && l < L - 1) st_flag(&flags[PFLAG(l)], (uint32_t)(t + 1));
        }
    }
#undef LDA8
}

__global__ __launch_bounds__(64)
void mlp2_kernel(const float* __restrict__ fin, const float* __restrict__ W2a,
                 const float* __restrict__ b2a, const float* __restrict__ W2b,
                 const float* __restrict__ b2b, float* __restrict__ out) {
    const int bt  = blockIdx.x;   // b*T + t
    const int tid = threadIdx.x;
    __shared__ float sx[H];
    __shared__ float sh[50];
    for (int i = tid; i < H; i += 64) sx[i] = fin[(size_t)bt * H + i];
    __syncthreads();
    if (tid < 50) {
        float a = b2a[tid];
        const float* w = W2a + (size_t)tid * H;
        for (int k = 0; k < H; ++k) a += w[k] * sx[k];
        sh[tid] = fmaxf(a, 0.0f);
    }
    __syncthreads();
    if (tid < 24) {
        float a = b2b[tid];
        const float* w = W2b + (size_t)tid * 50;
#pragma unroll
        for (int m = 0; m < 50; ++m) a += w[m] * sh[m];
        out[(size_t)bt * 24 + tid] = a;
    }
}

extern "C" void kernel_launch(void* const* d_in, const int* in_sizes, int n_in,
                              void* d_out, int out_size, void* d_ws, size_t ws_size,
                              hipStream_t stream) {
    const float* x    = (const float*)d_in[0];
    const float* W1   = (const float*)d_in[1];
    const float* b1   = (const float*)d_in[2];
    const float* Wih  = (const float*)d_in[3];
    const float* Whh  = (const float*)d_in[4];
    const float* bihp = (const float*)d_in[5];
    const float* bhhp = (const float*)d_in[6];
    const float* W2a  = (const float*)d_in[7];
    const float* b2a  = (const float*)d_in[8];
    const float* W2b  = (const float*)d_in[9];
    const float* b2b  = (const float*)d_in[10];
    float* out = (float*)d_out;
    float* ws  = (float*)d_ws;

    // fp8 zone: L*4*169 frags * 64 lanes * 8 B = 69.2 MB
    const size_t wm8_u32 = (size_t)L * 4 * NFRAG * 64 * 2;
    const size_t ring_u32_per_R = (size_t)(L - 1) * B * H / 2;  // f16 ring per R unit

    int R = 8; bool fast = false; size_t offwm = 0;
    for (;;) {
        size_t o = (OFF_RING + (size_t)R * ring_u32_per_R + 3) & ~(size_t)3;  // 16B align
        if ((o + wm8_u32) * 4ull <= ws_size) { fast = true; offwm = o; break; }
        if (R == 1) break;
        R >>= 1;
    }
    if (!fast) {
        R = 8;
        while (R > 1 && (OFF_RING + (size_t)R * ring_u32_per_R) * 4ull > ws_size)
            R >>= 1;
    }
    u64t* Wm8 = (u64t*)(ws + offwm);

    init_flags<<<32, 256, 0, stream>>>((uint32_t*)d_ws);
    mlp1_kernel<<<(B * T * H + 255) / 256, 256, 0, stream>>>(x, W1, b1,
                                                             (uint16_t*)(ws + OFF_H0));
    if (fast) {
        const size_t conv_threads = (size_t)L * 4 * NFRAG * 64;
        convert_weights_mfma<<<(int)((conv_threads + 255) / 256), 256, 0, stream>>>(
            Wih, Whh, Wm8);
        lstm_pipeline<true><<<L, 256, 0, stream>>>(Wm8, Wih, Whh, bihp, bhhp, ws, R);
    } else {
        lstm_pipeline<false><<<L, 256, 0, stream>>>(Wm8, Wih, Whh, bihp, bhhp, ws, R);
    }
    mlp2_kernel<<<B * T, 64, 0, stream>>>(ws + OFF_FINAL, W2a, b2a, W2b, b2b, out);
}

// Round 4
// 2844.573 us; speedup vs baseline: 2.8306x; 1.0314x over previous
//
#include <hip/hip_runtime.h>
#include <hip/hip_bf16.h>
#include <stdint.h>

#define B 8
#define T 256
#define DIN 6
#define H 200
#define G 800   // 4*H, ifgo gate order
#define L 200

#define NT 13       // N tiles per gate (208 rows, 200 real)
#define KT 13       // K tiles (416 cols, 400 real)
#define NFRAG 169   // NT*KT fragments per (layer,gate), all fp8
#define F_RG 117    // kt 0..8  -> registers (u64/lane each)
#define F_LD 52     // kt 9..12 -> LDS resident
#define XPAD 424    // xh8 row stride (fp8 bytes): 424 = conflict-free for b64 reads

// ws layout (float/uint32 elements):
#define OFF_H0    8192                       // h0 f16 [t][word][j][4b]: B*T*H halves
#define OFF_FINAL (OFF_H0 + (B*T*H)/2)       // final f32 [b][t][j]
#define OFF_RING  (OFF_FINAL + B*T*H)        // ring f16 [slot][word][j][4b]
#define PFLAG(l)  ((l) * 16)
#define CFLAG(l)  (4096 + (l) * 16)

typedef _Float16 half8 __attribute__((ext_vector_type(8)));
typedef float f32x4 __attribute__((ext_vector_type(4)));
typedef unsigned long long u64t;

__device__ __forceinline__ float fsig(float x) {
    return 1.0f / (1.0f + __expf(-x));
}
__device__ __forceinline__ float ftanh(float x) {
    float e = __expf(2.0f * x);
    return 1.0f - 2.0f / (e + 1.0f);
}

__device__ __forceinline__ uint32_t ld_flag(const uint32_t* p) {
    return __hip_atomic_load(p, __ATOMIC_RELAXED, __HIP_MEMORY_SCOPE_AGENT);
}
__device__ __forceinline__ void st_flag(uint32_t* p, uint32_t v) {
    __hip_atomic_store(p, v, __ATOMIC_RELAXED, __HIP_MEMORY_SCOPE_AGENT);
}
__device__ __forceinline__ u64t ld_u64(const u64t* p) {
    return __hip_atomic_load(p, __ATOMIC_RELAXED, __HIP_MEMORY_SCOPE_AGENT);
}
__device__ __forceinline__ void st_u64(u64t* p, u64t v) {
    __hip_atomic_store(p, v, __ATOMIC_RELAXED, __HIP_MEMORY_SCOPE_AGENT);
}
__device__ __forceinline__ uint8_t to_fp8(float v) {
    return (uint8_t)(__builtin_amdgcn_cvt_pk_fp8_f32(v, v, 0u, false) & 0xffu);
}

__global__ void init_flags(uint32_t* ws) {
    int i = blockIdx.x * 256 + threadIdx.x;
    if (i < 8192) ws[i] = 0u;
}

// mlp1: h0 as f16 in [t][word][j][b&3] layout (word = b>>2), ring-compatible.
__global__ void mlp1_kernel(const float* __restrict__ x, const float* __restrict__ W1,
                            const float* __restrict__ b1, uint16_t* __restrict__ h0h) {
    int idx = blockIdx.x * 256 + threadIdx.x;
    if (idx >= B * T * H) return;
    int j  = idx % H;
    int bt = idx / H;          // bt = b*T + t
    int b  = bt / T;
    int t  = bt % T;
    const float* xr = x  + (size_t)bt * DIN;
    const float* wr = W1 + (size_t)j * DIN;
    float a = b1[j];
#pragma unroll
    for (int k = 0; k < DIN; ++k) a += xr[k] * wr[k];
    _Float16 h = (_Float16)a;
    h0h[((size_t)(t * 2 + (b >> 2)) * H + j) * 4 + (b & 3)] = __builtin_bit_cast(uint16_t, h);
}

// All weights fp8 e4m3. One thread per (l, g, frag, lane); writes u64 (8 fp8).
// frag f = kt*13+nt; element j: r = g*200 + nt*16 + (lane&15),
// k = kt*32 + (lane>>4)*8 + j ; Wcat[r][k] = k<200 ? Wih : Whh[k-200]; 0 pad.
__global__ void convert_weights_mfma(const float* __restrict__ Wih,
                                     const float* __restrict__ Whh,
                                     u64t* __restrict__ Wm8) {
    size_t idx = (size_t)blockIdx.x * 256 + threadIdx.x;
    const size_t TOT = (size_t)L * 4 * NFRAG * 64;
    if (idx >= TOT) return;
    int lane = (int)(idx & 63);
    size_t r0 = idx >> 6;
    int f = (int)(r0 % NFRAG); r0 /= NFRAG;
    int g = (int)(r0 % 4);
    int l = (int)(r0 / 4);
    int kt = f / 13, nt = f % 13;
    int rl = nt * 16 + (lane & 15);
    int r  = g * 200 + rl;
    float v[8];
#pragma unroll
    for (int j = 0; j < 8; ++j) {
        int k = kt * 32 + (lane >> 4) * 8 + j;
        float xx = 0.0f;
        if (rl < 200 && k < 400)
            xx = (k < 200) ? Wih[((size_t)l * G + r) * 200 + k]
                           : Whh[((size_t)l * G + r) * 200 + (k - 200)];
        v[j] = xx;
    }
    uint32_t lo = __builtin_amdgcn_cvt_pk_fp8_f32(v[0], v[1], 0u, false);
    lo = __builtin_amdgcn_cvt_pk_fp8_f32(v[2], v[3], lo, true);
    uint32_t hi = __builtin_amdgcn_cvt_pk_fp8_f32(v[4], v[5], 0u, false);
    hi = __builtin_amdgcn_cvt_pk_fp8_f32(v[6], v[7], hi, true);
    Wm8[((size_t)(l * 4 + g) * NFRAG + f) * 64 + lane] = (u64t)lo | ((u64t)hi << 32);
}

#define MFMA8(a, b, c)  __builtin_amdgcn_mfma_f32_16x16x32_fp8_fp8((a), (b), (c), 0, 0, 0)

// One workgroup per layer, 256 threads = 4 waves, wave w = gate w.
// XCD-affinity layer mapping: XCD = blockIdx%8 (round-robin dispatch), so
// l = (bx&7)*25 + (bx>>3) puts 25 CONSECUTIVE layers on one XCD -> 199/207
// producer->consumer handshakes (flag + ring slot) stay in the local 4MB L2
// instead of crossing the chip through L3/fabric.
// ALL weights resident: kt0..8 in registers (117 u64/lane), kt9..12 in LDS.
template <bool FAST>
__global__ __launch_bounds__(256, 1)
void lstm_pipeline(const u64t* __restrict__ Wm8,
                   const float* __restrict__ Wih, const float* __restrict__ Whh,
                   const float* __restrict__ bih, const float* __restrict__ bhh,
                   float* ws, int R) {
#pragma clang fp contract(fast)
    const int bx    = blockIdx.x;
    const int l     = ((bx & 7) * 25) + (bx >> 3);   // bijective on [0,200)
    const int tid   = threadIdx.x;
    const int wv    = tid >> 6;      // gate index
    const int lane  = tid & 63;
    const int rmask = R - 1;         // R is a power of two

    const u64t* h0h = (const u64t*)(ws + OFF_H0);
    float*    finalbuf = ws + OFF_FINAL;
    u64t*     ring     = (u64t*)(ws + OFF_RING);   // [slot][word][j][4b] f16, 400 u64/slot
    uint32_t* flags    = (uint32_t*)ws;

    __shared__ __align__(16) uint8_t  xh8[16 * XPAD];      // [m][k] fp8 A, k=0..415 (+pad)
    __shared__ __align__(16) float    zl[4 * 8 * 208];     // [g][b][nj]
    __shared__ __align__(16) u64t     wl8[4 * F_LD * 64];  // fp8 weight zone kt9..12

    // zero xh8 once: pad rows 8..15, pad cols 400.., and h-cols for t=0 (h_{-1}=0)
    for (int i = tid; i < (16 * XPAD) / 16; i += 256)
        ((uint4*)xh8)[i] = make_uint4(0u, 0u, 0u, 0u);

    const bool actj = tid < H;
    float cs[B];
    float bs[4];
    if (actj) {
#pragma unroll
        for (int g = 0; g < 4; ++g)
            bs[g] = bih[(size_t)l * G + g * H + tid] + bhh[(size_t)l * G + g * H + tid];
#pragma unroll
        for (int b = 0; b < B; ++b) cs[b] = 0.0f;
    }

    const u64t* wq8 = Wm8 + (size_t)(l * 4 + wv) * NFRAG * 64;

    u64t wr8[F_RG];
    if (FAST) {
#pragma unroll
        for (int f = 0; f < F_RG; ++f) wr8[f] = wq8[f * 64 + lane];
        for (int i = 0; i < F_LD; ++i)
            wl8[(wv * F_LD + i) * 64 + lane] = wq8[(F_RG + i) * 64 + lane];
    }
    float* xhf = (float*)wl8;   // fallback-only f32 view [b*416 + col]
    __syncthreads();

#define LDA8(kt) (*(const long*)&xh8[(lane & 15) * XPAD + (kt) * 32 + (lane >> 4) * 8])

    for (int t = 0; t < T; ++t) {
        if (FAST) {
            f32x4 acc[NT];
#pragma unroll
            for (int nt = 0; nt < NT; ++nt) acc[nt] = (f32x4){0.f, 0.f, 0.f, 0.f};

            // ---- h-part: kt 7..8 (registers) -- uses own h_{t-1} ----
#pragma unroll
            for (int kt = 7; kt < 9; ++kt) {
                long a = LDA8(kt);
#pragma unroll
                for (int nt = 0; nt < NT; ++nt)
                    acc[nt] = MFMA8(a, (long)wr8[kt * NT + nt], acc[nt]);
            }
            // ---- h-part: kt 9..12 (LDS) ----
#pragma unroll
            for (int kt = 9; kt < 13; ++kt) {
                long a = LDA8(kt);
#pragma unroll
                for (int nt = 0; nt < NT; ++nt) {
                    u64t w = wl8[(wv * F_LD + (kt - 9) * NT + nt) * 64 + lane];
                    acc[nt] = MFMA8(a, (long)w, acc[nt]);
                }
            }

            // ---- wait for producer / ring backpressure (all threads poll) ----
            if (l > 0) {
                const uint32_t need = (uint32_t)(t + 1);
                while (ld_flag(&flags[PFLAG(l - 1)]) < need) __builtin_amdgcn_s_sleep(1);
            }
            if (l < L - 1 && t >= R) {
                const uint32_t need = (uint32_t)(t - R + 1);
                while (ld_flag(&flags[CFLAG(l + 1)]) < need) __builtin_amdgcn_s_sleep(1);
            }

            // ---- stage x_t: f16 [word][j][4b] -> fp8 LDS xh8[b][j] ----
            if (actj) {
                u64t p0, p1;
                if (l == 0) {
                    p0 = h0h[(size_t)(t * 2 + 0) * H + tid];
                    p1 = h0h[(size_t)(t * 2 + 1) * H + tid];
                } else {
                    const u64t* s = ring + ((size_t)(l - 1) * R + (t & rmask)) * 400;
                    p0 = ld_u64(s + tid);
                    p1 = ld_u64(s + 200 + tid);
                }
#pragma unroll
                for (int b = 0; b < 4; ++b) {
                    float f0 = (float)__builtin_bit_cast(_Float16, (uint16_t)(p0 >> (16 * b)));
                    float f1 = (float)__builtin_bit_cast(_Float16, (uint16_t)(p1 >> (16 * b)));
                    xh8[b * XPAD + tid]       = to_fp8(f0);
                    xh8[(b + 4) * XPAD + tid] = to_fp8(f1);
                }
            }
            __syncthreads();
            if (tid == 0 && l > 0) st_flag(&flags[CFLAG(l)], (uint32_t)(t + 1));

            // ---- x-part: kt 0..6 (registers); kt6 = x 192..199 + own-h 200..223 ----
#pragma unroll
            for (int kt = 0; kt < 7; ++kt) {
                long a = LDA8(kt);
#pragma unroll
                for (int nt = 0; nt < NT; ++nt)
                    acc[nt] = MFMA8(a, (long)wr8[kt * NT + nt], acc[nt]);
            }

            // write gate pre-activations: D row m=(lane>>4)*4+reg (batch), col n=lane&15
            if ((lane >> 4) < 2) {
#pragma unroll
                for (int nt = 0; nt < NT; ++nt) {
                    int nj = nt * 16 + (lane & 15);
#pragma unroll
                    for (int r = 0; r < 4; ++r) {
                        int b = (lane >> 4) * 4 + r;
                        zl[(wv * 8 + b) * 208 + nj] = acc[nt][r];
                    }
                }
            }
            __syncthreads();   // z complete; also guards xh8 h-col overwrite below

            if (actj) {
                u64t p0 = 0ull, p1 = 0ull;
#pragma unroll
                for (int b = 0; b < B; ++b) {
                    float zi = zl[(0 * 8 + b) * 208 + tid] + bs[0];
                    float zf = zl[(1 * 8 + b) * 208 + tid] + bs[1];
                    float zg = zl[(2 * 8 + b) * 208 + tid] + bs[2];
                    float zo = zl[(3 * 8 + b) * 208 + tid] + bs[3];
                    float ig = fsig(zi);
                    float fg = fsig(zf);
                    float gg = ftanh(zg);
                    float og = fsig(zo);
                    float c  = fg * cs[b] + ig * gg;
                    cs[b] = c;
                    float h = og * ftanh(c);
                    xh8[b * XPAD + 200 + tid] = to_fp8(h);
                    _Float16 hh = (_Float16)h;
                    u64t u = (u64t)__builtin_bit_cast(uint16_t, hh);
                    if (b < 4) p0 |= u << (16 * b);
                    else       p1 |= u << (16 * (b - 4));
                    if (l == L - 1) finalbuf[((size_t)b * T + t) * H + tid] = h;
                }
                if (l < L - 1) {
                    u64t* dst = ring + ((size_t)l * R + (t & rmask)) * 400;
                    st_u64(dst + tid, p0);          // word 0: dense 200 u64
                    st_u64(dst + 200 + tid, p1);    // word 1: dense 200 u64
                }
            }
            asm volatile("s_waitcnt vmcnt(0)" ::: "memory");
            __syncthreads();
            if (tid == 0 && l < L - 1) st_flag(&flags[PFLAG(l)], (uint32_t)(t + 1));
        } else {
            // ---------------- f32 fallback (slow but correct-enough) ----------------
            if (l > 0) {
                const uint32_t need = (uint32_t)(t + 1);
                while (ld_flag(&flags[PFLAG(l - 1)]) < need) __builtin_amdgcn_s_sleep(1);
            }
            if (l < L - 1 && t >= R) {
                const uint32_t need = (uint32_t)(t - R + 1);
                while (ld_flag(&flags[CFLAG(l + 1)]) < need) __builtin_amdgcn_s_sleep(1);
            }
            if (actj) {
                u64t p0, p1;
                if (l == 0) {
                    p0 = h0h[(size_t)(t * 2 + 0) * H + tid];
                    p1 = h0h[(size_t)(t * 2 + 1) * H + tid];
                } else {
                    const u64t* s = ring + ((size_t)(l - 1) * R + (t & rmask)) * 400;
                    p0 = ld_u64(s + tid);
                    p1 = ld_u64(s + 200 + tid);
                }
#pragma unroll
                for (int b = 0; b < 4; ++b) {
                    xhf[b * 416 + tid]       = (float)__builtin_bit_cast(_Float16, (uint16_t)(p0 >> (16 * b)));
                    xhf[(b + 4) * 416 + tid] = (float)__builtin_bit_cast(_Float16, (uint16_t)(p1 >> (16 * b)));
                }
            }
            __syncthreads();
            if (tid == 0 && l > 0) st_flag(&flags[CFLAG(l)], (uint32_t)(t + 1));

            if (actj) {
                const float* wi0 = Wih + (size_t)l * G * H;
                const float* wh0 = Whh + (size_t)l * G * H;
                float acc[4][B];
#pragma unroll
                for (int g = 0; g < 4; ++g)
#pragma unroll
                    for (int b = 0; b < B; ++b) acc[g][b] = 0.0f;
                for (int k2 = 0; k2 < 200; ++k2) {
                    float2 wvv[4];
                    if (k2 < 100) {
#pragma unroll
                        for (int g = 0; g < 4; ++g)
                            wvv[g] = *(const float2*)&wi0[((size_t)(g * 200 + tid)) * 200 + 2 * k2];
                    } else {
#pragma unroll
                        for (int g = 0; g < 4; ++g)
                            wvv[g] = *(const float2*)&wh0[((size_t)(g * 200 + tid)) * 200 + 2 * (k2 - 100)];
                    }
#pragma unroll
                    for (int b = 0; b < B; ++b) {
                        float2 xv = *(const float2*)&xhf[b * 416 + 2 * k2];
#pragma unroll
                        for (int g = 0; g < 4; ++g) {
                            acc[g][b] += wvv[g].x * xv.x;
                            acc[g][b] += wvv[g].y * xv.y;
                        }
                    }
                }
#pragma unroll
                for (int g = 0; g < 4; ++g)
#pragma unroll
                    for (int b = 0; b < B; ++b)
                        zl[(g * 8 + b) * 208 + tid] = acc[g][b];
            }
            __syncthreads();

            if (actj) {
                u64t p0 = 0ull, p1 = 0ull;
#pragma unroll
                for (int b = 0; b < B; ++b) {
                    float zi = zl[(0 * 8 + b) * 208 + tid] + bs[0];
                    float zf = zl[(1 * 8 + b) * 208 + tid] + bs[1];
                    float zg = zl[(2 * 8 + b) * 208 + tid] + bs[2];
                    float zo = zl[(3 * 8 + b) * 208 + tid] + bs[3];
                    float ig = fsig(zi);
                    float fg = fsig(zf);
                    float gg = ftanh(zg);
                    float og = fsig(zo);
                    float c  = fg * cs[b] + ig * gg;
                    cs[b] = c;
                    float h = og * ftanh(c);
                    xhf[b * 416 + 200 + tid] = h;
                    _Float16 hh = (_Float16)h;
                    u64t u = (u64t)__builtin_bit_cast(uint16_t, hh);
                    if (b < 4) p0 |= u << (16 * b);
                    else       p1 |= u << (16 * (b - 4));
                    if (l == L - 1) finalbuf[((size_t)b * T + t) * H + tid] = h;
                }
                if (l < L - 1) {
                    u64t* dst = ring + ((size_t)l * R + (t & rmask)) * 400;
                    st_u64(dst + tid, p0);
                    st_u64(dst + 200 + tid, p1);
                }
            }
            asm volatile("s_waitcnt vmcnt(0)" ::: "memory");
            __syncthreads();
            if (tid == 0 && l < L - 1) st_flag(&flags[PFLAG(l)], (uint32_t)(t + 1));
        }
    }
#undef LDA8
}

__global__ __launch_bounds__(64)
void mlp2_kernel(const float* __restrict__ fin, const float* __restrict__ W2a,
                 const float* __restrict__ b2a, const float* __restrict__ W2b,
                 const float* __restrict__ b2b, float* __restrict__ out) {
    const int bt  = blockIdx.x;   // b*T + t
    const int tid = threadIdx.x;
    __shared__ float sx[H];
    __shared__ float sh[50];
    for (int i = tid; i < H; i += 64) sx[i] = fin[(size_t)bt * H + i];
    __syncthreads();
    if (tid < 50) {
        float a = b2a[tid];
        const float* w = W2a + (size_t)tid * H;
        for (int k = 0; k < H; ++k) a += w[k] * sx[k];
        sh[tid] = fmaxf(a, 0.0f);
    }
    __syncthreads();
    if (tid < 24) {
        float a = b2b[tid];
        const float* w = W2b + (size_t)tid * 50;
#pragma unroll
        for (int m = 0; m < 50; ++m) a += w[m] * sh[m];
        out[(size_t)bt * 24 + tid] = a;
    }
}

extern "C" void kernel_launch(void* const* d_in, const int* in_sizes, int n_in,
                              void* d_out, int out_size, void* d_ws, size_t ws_size,
                              hipStream_t stream) {
    const float* x    = (const float*)d_in[0];
    const float* W1   = (const float*)d_in[1];
    const float* b1   = (const float*)d_in[2];
    const float* Wih  = (const float*)d_in[3];
    const float* Whh  = (const float*)d_in[4];
    const float* bihp = (const float*)d_in[5];
    const float* bhhp = (const float*)d_in[6];
    const float* W2a  = (const float*)d_in[7];
    const float* b2a  = (const float*)d_in[8];
    const float* W2b  = (const float*)d_in[9];
    const float* b2b  = (const float*)d_in[10];
    float* out = (float*)d_out;
    float* ws  = (float*)d_ws;

    // fp8 zone: L*4*169 frags * 64 lanes * 8 B = 69.2 MB
    const size_t wm8_u32 = (size_t)L * 4 * NFRAG * 64 * 2;
    const size_t ring_u32_per_R = (size_t)(L - 1) * B * H / 2;  // f16 ring per R unit

    int R = 8; bool fast = false; size_t offwm = 0;
    for (;;) {
        size_t o = (OFF_RING + (size_t)R * ring_u32_per_R + 3) & ~(size_t)3;  // 16B align
        if ((o + wm8_u32) * 4ull <= ws_size) { fast = true; offwm = o; break; }
        if (R == 1) break;
        R >>= 1;
    }
    if (!fast) {
        R = 8;
        while (R > 1 && (OFF_RING + (size_t)R * ring_u32_per_R) * 4ull > ws_size)
            R >>= 1;
    }
    u64t* Wm8 = (u64t*)(ws + offwm);

    init_flags<<<32, 256, 0, stream>>>((uint32_t*)d_ws);
    mlp1_kernel<<<(B * T * H + 255) / 256, 256, 0, stream>>>(x, W1, b1,
                                                             (uint16_t*)(ws + OFF_H0));
    if (fast) {
        const size_t conv_threads = (size_t)L * 4 * NFRAG * 64;
        convert_weights_mfma<<<(int)((conv_threads + 255) / 256), 256, 0, stream>>>(
            Wih, Whh, Wm8);
        lstm_pipeline<true><<<L, 256, 0, stream>>>(Wm8, Wih, Whh, bihp, bhhp, ws, R);
    } else {
        lstm_pipeline<false><<<L, 256, 0, stream>>>(Wm8, Wih, Whh, bihp, bhhp, ws, R);
    }
    mlp2_kernel<<<B * T, 64, 0, stream>>>(ws + OFF_FINAL, W2a, b2a, W2b, b2b, out);
}

// Round 5
// 2782.044 us; speedup vs baseline: 2.8942x; 1.0225x over previous
//
#include <hip/hip_runtime.h>
#include <hip/hip_bf16.h>
#include <stdint.h>

#define B 8
#define T 256
#define DIN 6
#define H 200
#define G 800   // 4*H, ifgo gate order
#define L 200

#define NT 13       // N tiles per gate (208 rows, 200 real)
#define KT 13       // K tiles (416 cols, 400 real)
#define NFRAG 169   // NT*KT fragments per (layer,gate), all fp8
#define F_RG 117    // kt 0..8  -> registers (u64/lane each)
#define F_LD 52     // kt 9..12 -> LDS resident
#define XPAD 424    // xh8 row stride (fp8 bytes): conflict-free for b64 reads

#define SENT16 0xFFFFu    // f16 -NaN: impossible for h = og*tanh(c) (finite)
#define SENT64 0xFFFFFFFFFFFFFFFFull

// ws layout (float/uint32 elements):
#define OFF_H0    8192                       // h0 f16 [t][word][j][4b]: B*T*H halves
#define OFF_FINAL (OFF_H0 + (B*T*H)/2)       // final f32 [b][t][j]
#define OFF_RING  (OFF_FINAL + B*T*H)        // ring f16 [slot][word][j][4b]
#define CFLAG(l)  (4096 + (l) * 16)          // consumer-progress flags (backpressure)

typedef _Float16 half8 __attribute__((ext_vector_type(8)));
typedef float f32x4 __attribute__((ext_vector_type(4)));
typedef unsigned long long u64t;

__device__ __forceinline__ float fsig(float x) {
    return 1.0f / (1.0f + __expf(-x));
}
__device__ __forceinline__ float ftanh(float x) {
    float e = __expf(2.0f * x);
    return 1.0f - 2.0f / (e + 1.0f);
}

__device__ __forceinline__ uint32_t ld_flag(const uint32_t* p) {
    return __hip_atomic_load(p, __ATOMIC_RELAXED, __HIP_MEMORY_SCOPE_AGENT);
}
__device__ __forceinline__ void st_flag(uint32_t* p, uint32_t v) {
    __hip_atomic_store(p, v, __ATOMIC_RELAXED, __HIP_MEMORY_SCOPE_AGENT);
}
__device__ __forceinline__ u64t ld_u64(const u64t* p) {
    return __hip_atomic_load(p, __ATOMIC_RELAXED, __HIP_MEMORY_SCOPE_AGENT);
}
__device__ __forceinline__ void st_u64(u64t* p, u64t v) {
    __hip_atomic_store(p, v, __ATOMIC_RELAXED, __HIP_MEMORY_SCOPE_AGENT);
}
__device__ __forceinline__ uint8_t to_fp8(float v) {
    return (uint8_t)(__builtin_amdgcn_cvt_pk_fp8_f32(v, v, 0u, false) & 0xffu);
}

__global__ void init_flags(uint32_t* ws) {
    int i = blockIdx.x * 256 + threadIdx.x;
    if (i < 8192) ws[i] = 0u;
}

// Pre-arm the whole ring with the sentinel pattern.
__global__ void fill_ring(u64t* __restrict__ ring, long n) {
    long i = (long)blockIdx.x * 256 + threadIdx.x;
    if (i < n) ring[i] = SENT64;
}

// mlp1: h0 as f16 in [t][word][j][b&3] layout (word = b>>2), ring-compatible.
__global__ void mlp1_kernel(const float* __restrict__ x, const float* __restrict__ W1,
                            const float* __restrict__ b1, uint16_t* __restrict__ h0h) {
    int idx = blockIdx.x * 256 + threadIdx.x;
    if (idx >= B * T * H) return;
    int j  = idx % H;
    int bt = idx / H;          // bt = b*T + t
    int b  = bt / T;
    int t  = bt % T;
    const float* xr = x  + (size_t)bt * DIN;
    const float* wr = W1 + (size_t)j * DIN;
    float a = b1[j];
#pragma unroll
    for (int k = 0; k < DIN; ++k) a += xr[k] * wr[k];
    _Float16 h = (_Float16)a;
    h0h[((size_t)(t * 2 + (b >> 2)) * H + j) * 4 + (b & 3)] = __builtin_bit_cast(uint16_t, h);
}

// All weights fp8 e4m3. One thread per (l, g, frag, lane); writes u64 (8 fp8).
// frag f = kt*13+nt; element j: r = g*200 + nt*16 + (lane&15),
// k = kt*32 + (lane>>4)*8 + j ; Wcat[r][k] = k<200 ? Wih : Whh[k-200]; 0 pad.
__global__ void convert_weights_mfma(const float* __restrict__ Wih,
                                     const float* __restrict__ Whh,
                                     u64t* __restrict__ Wm8) {
    size_t idx = (size_t)blockIdx.x * 256 + threadIdx.x;
    const size_t TOT = (size_t)L * 4 * NFRAG * 64;
    if (idx >= TOT) return;
    int lane = (int)(idx & 63);
    size_t r0 = idx >> 6;
    int f = (int)(r0 % NFRAG); r0 /= NFRAG;
    int g = (int)(r0 % 4);
    int l = (int)(r0 / 4);
    int kt = f / 13, nt = f % 13;
    int rl = nt * 16 + (lane & 15);
    int r  = g * 200 + rl;
    float v[8];
#pragma unroll
    for (int j = 0; j < 8; ++j) {
        int k = kt * 32 + (lane >> 4) * 8 + j;
        float xx = 0.0f;
        if (rl < 200 && k < 400)
            xx = (k < 200) ? Wih[((size_t)l * G + r) * 200 + k]
                           : Whh[((size_t)l * G + r) * 200 + (k - 200)];
        v[j] = xx;
    }
    uint32_t lo = __builtin_amdgcn_cvt_pk_fp8_f32(v[0], v[1], 0u, false);
    lo = __builtin_amdgcn_cvt_pk_fp8_f32(v[2], v[3], lo, true);
    uint32_t hi = __builtin_amdgcn_cvt_pk_fp8_f32(v[4], v[5], 0u, false);
    hi = __builtin_amdgcn_cvt_pk_fp8_f32(v[6], v[7], hi, true);
    Wm8[((size_t)(l * 4 + g) * NFRAG + f) * 64 + lane] = (u64t)lo | ((u64t)hi << 32);
}

#define MFMA8(a, b, c)  __builtin_amdgcn_mfma_f32_16x16x32_fp8_fp8((a), (b), (c), 0, 0, 0)

// One workgroup per layer, 256 threads = 4 waves, wave w = gate w.
// DATA-EMBEDDED HANDSHAKE: ring pre-armed with sentinel (f16 NaN pattern).
// Producer fire-and-forgets its 2 u64 ring stores (no drain, no flag).
// Consumer spins directly on its own ring words (1 L3 round trip delivers
// validity AND payload), re-arms the sentinel, and publishes backpressure
// CFLAG after a vmcnt(0) that makes the re-arm visible.
// ALL weights resident: kt0..8 in registers (117 u64/lane), kt9..12 in LDS.
template <bool FAST>
__global__ __launch_bounds__(256, 1)
void lstm_pipeline(const u64t* __restrict__ Wm8,
                   const float* __restrict__ Wih, const float* __restrict__ Whh,
                   const float* __restrict__ bih, const float* __restrict__ bhh,
                   float* ws, int R) {
#pragma clang fp contract(fast)
    const int bx    = blockIdx.x;
    const int l     = ((bx & 7) * 25) + (bx >> 3);   // 25 consecutive layers per XCD
    const int tid   = threadIdx.x;
    const int wv    = tid >> 6;      // gate index
    const int lane  = tid & 63;
    const int rmask = R - 1;         // R is a power of two

    const u64t* h0h = (const u64t*)(ws + OFF_H0);
    float*    finalbuf = ws + OFF_FINAL;
    u64t*     ring     = (u64t*)(ws + OFF_RING);   // [slot][word][j][4b] f16, 400 u64/slot
    uint32_t* flags    = (uint32_t*)ws;

    __shared__ __align__(16) uint8_t  xh8[16 * XPAD];      // [m][k] fp8 A, k=0..415 (+pad)
    __shared__ __align__(16) float    zl[4 * 8 * 208];     // [g][b][nj]
    __shared__ __align__(16) u64t     wl8[4 * F_LD * 64];  // fp8 weight zone kt9..12

    // zero xh8 once: pad rows 8..15, pad cols 400.., and h-cols for t=0 (h_{-1}=0)
    for (int i = tid; i < (16 * XPAD) / 16; i += 256)
        ((uint4*)xh8)[i] = make_uint4(0u, 0u, 0u, 0u);

    const bool actj = tid < H;
    float cs[B];
    float bs[4];
    if (actj) {
#pragma unroll
        for (int g = 0; g < 4; ++g)
            bs[g] = bih[(size_t)l * G + g * H + tid] + bhh[(size_t)l * G + g * H + tid];
#pragma unroll
        for (int b = 0; b < B; ++b) cs[b] = 0.0f;
    }

    const u64t* wq8 = Wm8 + (size_t)(l * 4 + wv) * NFRAG * 64;

    u64t wr8[F_RG];
    if (FAST) {
#pragma unroll
        for (int f = 0; f < F_RG; ++f) wr8[f] = wq8[f * 64 + lane];
        for (int i = 0; i < F_LD; ++i)
            wl8[(wv * F_LD + i) * 64 + lane] = wq8[(F_RG + i) * 64 + lane];
    }
    float* xhf = (float*)wl8;   // fallback-only f32 view [b*416 + col]
    __syncthreads();

#define LDA8(kt) (*(const long*)&xh8[(lane & 15) * XPAD + (kt) * 32 + (lane >> 4) * 8])

    for (int t = 0; t < T; ++t) {
        if (FAST) {
            f32x4 acc[NT];
#pragma unroll
            for (int nt = 0; nt < NT; ++nt) acc[nt] = (f32x4){0.f, 0.f, 0.f, 0.f};

            // ---- h-part: kt 7..8 (registers) -- uses own h_{t-1} ----
#pragma unroll
            for (int kt = 7; kt < 9; ++kt) {
                long a = LDA8(kt);
#pragma unroll
                for (int nt = 0; nt < NT; ++nt)
                    acc[nt] = MFMA8(a, (long)wr8[kt * NT + nt], acc[nt]);
            }
            // ---- h-part: kt 9..12 (LDS) ----
#pragma unroll
            for (int kt = 9; kt < 13; ++kt) {
                long a = LDA8(kt);
#pragma unroll
                for (int nt = 0; nt < NT; ++nt) {
                    u64t w = wl8[(wv * F_LD + (kt - 9) * NT + nt) * 64 + lane];
                    acc[nt] = MFMA8(a, (long)w, acc[nt]);
                }
            }

            // ---- backpressure (slot for this t must have been consumed) ----
            if (l < L - 1 && t >= R) {
                const uint32_t need = (uint32_t)(t - R + 1);
                while (ld_flag(&flags[CFLAG(l + 1)]) < need) __builtin_amdgcn_s_sleep(1);
            }

            // ---- stage x_t: spin on ring DATA (sentinel protocol), re-arm, cvt ----
            if (actj) {
                u64t p0, p1;
                if (l == 0) {
                    p0 = h0h[(size_t)(t * 2 + 0) * H + tid];
                    p1 = h0h[(size_t)(t * 2 + 1) * H + tid];
                } else {
                    u64t* s = ring + ((size_t)(l - 1) * R + (t & rmask)) * 400;
                    p0 = ld_u64(s + tid);
                    p1 = ld_u64(s + 200 + tid);
                    while ((uint16_t)(p0 >> 48) == SENT16 ||
                           (uint16_t)(p1 >> 48) == SENT16) {
                        __builtin_amdgcn_s_sleep(1);
                        p0 = ld_u64(s + tid);
                        p1 = ld_u64(s + 200 + tid);
                    }
                    st_u64(s + tid, SENT64);         // re-arm for next wrap
                    st_u64(s + 200 + tid, SENT64);
                }
#pragma unroll
                for (int b = 0; b < 4; ++b) {
                    float f0 = (float)__builtin_bit_cast(_Float16, (uint16_t)(p0 >> (16 * b)));
                    float f1 = (float)__builtin_bit_cast(_Float16, (uint16_t)(p1 >> (16 * b)));
                    xh8[b * XPAD + tid]       = to_fp8(f0);
                    xh8[(b + 4) * XPAD + tid] = to_fp8(f1);
                }
            }
            // re-arm stores must be visible before CFLAG is published
            asm volatile("s_waitcnt vmcnt(0)" ::: "memory");
            __syncthreads();
            if (tid == 0 && l > 0) st_flag(&flags[CFLAG(l)], (uint32_t)(t + 1));

            // ---- x-part: kt 0..6 (registers); kt6 = x 192..199 + own-h 200..223 ----
#pragma unroll
            for (int kt = 0; kt < 7; ++kt) {
                long a = LDA8(kt);
#pragma unroll
                for (int nt = 0; nt < NT; ++nt)
                    acc[nt] = MFMA8(a, (long)wr8[kt * NT + nt], acc[nt]);
            }

            // write gate pre-activations: D row m=(lane>>4)*4+reg (batch), col n=lane&15
            if ((lane >> 4) < 2) {
#pragma unroll
                for (int nt = 0; nt < NT; ++nt) {
                    int nj = nt * 16 + (lane & 15);
#pragma unroll
                    for (int r = 0; r < 4; ++r) {
                        int b = (lane >> 4) * 4 + r;
                        zl[(wv * 8 + b) * 208 + nj] = acc[nt][r];
                    }
                }
            }
            __syncthreads();   // z complete; also guards xh8 h-col overwrite below

            if (actj) {
                u64t p0 = 0ull, p1 = 0ull;
#pragma unroll
                for (int b = 0; b < B; ++b) {
                    float zi = zl[(0 * 8 + b) * 208 + tid] + bs[0];
                    float zf = zl[(1 * 8 + b) * 208 + tid] + bs[1];
                    float zg = zl[(2 * 8 + b) * 208 + tid] + bs[2];
                    float zo = zl[(3 * 8 + b) * 208 + tid] + bs[3];
                    float ig = fsig(zi);
                    float fg = fsig(zf);
                    float gg = ftanh(zg);
                    float og = fsig(zo);
                    float c  = fg * cs[b] + ig * gg;
                    cs[b] = c;
                    float h = og * ftanh(c);
                    xh8[b * XPAD + 200 + tid] = to_fp8(h);
                    _Float16 hh = (_Float16)h;
                    u64t u = (u64t)__builtin_bit_cast(uint16_t, hh);
                    if (b < 4) p0 |= u << (16 * b);
                    else       p1 |= u << (16 * (b - 4));
                    if (l == L - 1) finalbuf[((size_t)b * T + t) * H + tid] = h;
                }
                if (l < L - 1) {
                    // fire-and-forget: data doubles as the readiness flag
                    u64t* dst = ring + ((size_t)l * R + (t & rmask)) * 400;
                    st_u64(dst + tid, p0);
                    st_u64(dst + 200 + tid, p1);
                }
            }
            __syncthreads();   // xh8 h-cols stable for next h-GEMM
        } else {
            // ---------------- f32 fallback (slow but correct-enough) ----------------
            if (l < L - 1 && t >= R) {
                const uint32_t need = (uint32_t)(t - R + 1);
                while (ld_flag(&flags[CFLAG(l + 1)]) < need) __builtin_amdgcn_s_sleep(1);
            }
            if (actj) {
                u64t p0, p1;
                if (l == 0) {
                    p0 = h0h[(size_t)(t * 2 + 0) * H + tid];
                    p1 = h0h[(size_t)(t * 2 + 1) * H + tid];
                } else {
                    u64t* s = ring + ((size_t)(l - 1) * R + (t & rmask)) * 400;
                    p0 = ld_u64(s + tid);
                    p1 = ld_u64(s + 200 + tid);
                    while ((uint16_t)(p0 >> 48) == SENT16 ||
                           (uint16_t)(p1 >> 48) == SENT16) {
                        __builtin_amdgcn_s_sleep(1);
                        p0 = ld_u64(s + tid);
                        p1 = ld_u64(s + 200 + tid);
                    }
                    st_u64(s + tid, SENT64);
                    st_u64(s + 200 + tid, SENT64);
                }
#pragma unroll
                for (int b = 0; b < 4; ++b) {
                    xhf[b * 416 + tid]       = (float)__builtin_bit_cast(_Float16, (uint16_t)(p0 >> (16 * b)));
                    xhf[(b + 4) * 416 + tid] = (float)__builtin_bit_cast(_Float16, (uint16_t)(p1 >> (16 * b)));
                }
            }
            asm volatile("s_waitcnt vmcnt(0)" ::: "memory");
            __syncthreads();
            if (tid == 0 && l > 0) st_flag(&flags[CFLAG(l)], (uint32_t)(t + 1));

            if (actj) {
                const float* wi0 = Wih + (size_t)l * G * H;
                const float* wh0 = Whh + (size_t)l * G * H;
                float acc[4][B];
#pragma unroll
                for (int g = 0; g < 4; ++g)
#pragma unroll
                    for (int b = 0; b < B; ++b) acc[g][b] = 0.0f;
                for (int k2 = 0; k2 < 200; ++k2) {
                    float2 wvv[4];
                    if (k2 < 100) {
#pragma unroll
                        for (int g = 0; g < 4; ++g)
                            wvv[g] = *(const float2*)&wi0[((size_t)(g * 200 + tid)) * 200 + 2 * k2];
                    } else {
#pragma unroll
                        for (int g = 0; g < 4; ++g)
                            wvv[g] = *(const float2*)&wh0[((size_t)(g * 200 + tid)) * 200 + 2 * (k2 - 100)];
                    }
#pragma unroll
                    for (int b = 0; b < B; ++b) {
                        float2 xv = *(const float2*)&xhf[b * 416 + 2 * k2];
#pragma unroll
                        for (int g = 0; g < 4; ++g) {
                            acc[g][b] += wvv[g].x * xv.x;
                            acc[g][b] += wvv[g].y * xv.y;
                        }
                    }
                }
#pragma unroll
                for (int g = 0; g < 4; ++g)
#pragma unroll
                    for (int b = 0; b < B; ++b)
                        zl[(g * 8 + b) * 208 + tid] = acc[g][b];
            }
            __syncthreads();

            if (actj) {
                u64t p0 = 0ull, p1 = 0ull;
#pragma unroll
                for (int b = 0; b < B; ++b) {
                    float zi = zl[(0 * 8 + b) * 208 + tid] + bs[0];
                    float zf = zl[(1 * 8 + b) * 208 + tid] + bs[1];
                    float zg = zl[(2 * 8 + b) * 208 + tid] + bs[2];
                    float zo = zl[(3 * 8 + b) * 208 + tid] + bs[3];
                    float ig = fsig(zi);
                    float fg = fsig(zf);
                    float gg = ftanh(zg);
                    float og = fsig(zo);
                    float c  = fg * cs[b] + ig * gg;
                    cs[b] = c;
                    float h = og * ftanh(c);
                    xhf[b * 416 + 200 + tid] = h;
                    _Float16 hh = (_Float16)h;
                    u64t u = (u64t)__builtin_bit_cast(uint16_t, hh);
                    if (b < 4) p0 |= u << (16 * b);
                    else       p1 |= u << (16 * (b - 4));
                    if (l == L - 1) finalbuf[((size_t)b * T + t) * H + tid] = h;
                }
                if (l < L - 1) {
                    u64t* dst = ring + ((size_t)l * R + (t & rmask)) * 400;
                    st_u64(dst + tid, p0);
                    st_u64(dst + 200 + tid, p1);
                }
            }
            __syncthreads();
        }
    }
#undef LDA8
}

__global__ __launch_bounds__(64)
void mlp2_kernel(const float* __restrict__ fin, const float* __restrict__ W2a,
                 const float* __restrict__ b2a, const float* __restrict__ W2b,
                 const float* __restrict__ b2b, float* __restrict__ out) {
    const int bt  = blockIdx.x;   // b*T + t
    const int tid = threadIdx.x;
    __shared__ float sx[H];
    __shared__ float sh[50];
    for (int i = tid; i < H; i += 64) sx[i] = fin[(size_t)bt * H + i];
    __syncthreads();
    if (tid < 50) {
        float a = b2a[tid];
        const float* w = W2a + (size_t)tid * H;
        for (int k = 0; k < H; ++k) a += w[k] * sx[k];
        sh[tid] = fmaxf(a, 0.0f);
    }
    __syncthreads();
    if (tid < 24) {
        float a = b2b[tid];
        const float* w = W2b + (size_t)tid * 50;
#pragma unroll
        for (int m = 0; m < 50; ++m) a += w[m] * sh[m];
        out[(size_t)bt * 24 + tid] = a;
    }
}

extern "C" void kernel_launch(void* const* d_in, const int* in_sizes, int n_in,
                              void* d_out, int out_size, void* d_ws, size_t ws_size,
                              hipStream_t stream) {
    const float* x    = (const float*)d_in[0];
    const float* W1   = (const float*)d_in[1];
    const float* b1   = (const float*)d_in[2];
    const float* Wih  = (const float*)d_in[3];
    const float* Whh  = (const float*)d_in[4];
    const float* bihp = (const float*)d_in[5];
    const float* bhhp = (const float*)d_in[6];
    const float* W2a  = (const float*)d_in[7];
    const float* b2a  = (const float*)d_in[8];
    const float* W2b  = (const float*)d_in[9];
    const float* b2b  = (const float*)d_in[10];
    float* out = (float*)d_out;
    float* ws  = (float*)d_ws;

    // fp8 zone: L*4*169 frags * 64 lanes * 8 B = 69.2 MB
    const size_t wm8_u32 = (size_t)L * 4 * NFRAG * 64 * 2;
    const size_t ring_u32_per_R = (size_t)(L - 1) * B * H / 2;  // f16 ring per R unit

    int R = 8; bool fast = false; size_t offwm = 0;
    for (;;) {
        size_t o = (OFF_RING + (size_t)R * ring_u32_per_R + 3) & ~(size_t)3;  // 16B align
        if ((o + wm8_u32) * 4ull <= ws_size) { fast = true; offwm = o; break; }
        if (R == 1) break;
        R >>= 1;
    }
    if (!fast) {
        R = 8;
        while (R > 1 && (OFF_RING + (size_t)R * ring_u32_per_R) * 4ull > ws_size)
            R >>= 1;
    }
    u64t* Wm8 = (u64t*)(ws + offwm);

    const long ring_u64 = (long)(L - 1) * R * 400;   // u64 words in the ring

    init_flags<<<32, 256, 0, stream>>>((uint32_t*)d_ws);
    fill_ring<<<(int)((ring_u64 + 255) / 256), 256, 0, stream>>>(
        (u64t*)(ws + OFF_RING), ring_u64);
    mlp1_kernel<<<(B * T * H + 255) / 256, 256, 0, stream>>>(x, W1, b1,
                                                             (uint16_t*)(ws + OFF_H0));
    if (fast) {
        const size_t conv_threads = (size_t)L * 4 * NFRAG * 64;
        convert_weights_mfma<<<(int)((conv_threads + 255) / 256), 256, 0, stream>>>(
            Wih, Whh, Wm8);
        lstm_pipeline<true><<<L, 256, 0, stream>>>(Wm8, Wih, Whh, bihp, bhhp, ws, R);
    } else {
        lstm_pipeline<false><<<L, 256, 0, stream>>>(Wm8, Wih, Whh, bihp, bhhp, ws, R);
    }
    mlp2_kernel<<<B * T, 64, 0, stream>>>(ws + OFF_FINAL, W2a, b2a, W2b, b2b, out);
}

// Round 6
// 2113.030 us; speedup vs baseline: 3.8105x; 1.3166x over previous
//
#include <hip/hip_runtime.h>
#include <hip/hip_bf16.h>
#include <stdint.h>

#define B 8
#define T 256
#define DIN 6
#define H 200
#define G 800   // 4*H, ifgo gate order
#define L 200

#define NT 13       // N tiles per gate (208 rows, 200 real)
#define KT 13       // K tiles (416 cols, 400 real)
#define NFRAG 169   // NT*KT fragments per (layer,gate), all fp8
#define F_RG 117    // kt 0..8  -> registers (split across 2 waves per gate)
#define F_LD 52     // kt 9..12 -> LDS resident
#define XPAD 424    // xh8 row stride (fp8 bytes): conflict-free for b64 reads

#define SENT16 0xFFFFu    // f16 -NaN: impossible for h = og*tanh(c) (finite)
#define SENT64 0xFFFFFFFFFFFFFFFFull

// ws layout (float/uint32 elements):
#define OFF_H0    8192                       // h0 f16 [t][word][j][4b]: B*T*H halves
#define OFF_FINAL (OFF_H0 + (B*T*H)/2)       // final f32 [b][t][j]
#define OFF_RING  (OFF_FINAL + B*T*H)        // ring f16 [slot][word][j][4b]
#define CFLAG(l)  (4096 + (l) * 16)          // consumer-progress flags (backpressure)

typedef _Float16 half8 __attribute__((ext_vector_type(8)));
typedef float f32x4 __attribute__((ext_vector_type(4)));
typedef unsigned long long u64t;

__device__ __forceinline__ float fsig(float x) {
    return 1.0f / (1.0f + __expf(-x));
}
__device__ __forceinline__ float ftanh(float x) {
    float e = __expf(2.0f * x);
    return 1.0f - 2.0f / (e + 1.0f);
}

__device__ __forceinline__ uint32_t ld_flag(const uint32_t* p) {
    return __hip_atomic_load(p, __ATOMIC_RELAXED, __HIP_MEMORY_SCOPE_AGENT);
}
__device__ __forceinline__ void st_flag(uint32_t* p, uint32_t v) {
    __hip_atomic_store(p, v, __ATOMIC_RELAXED, __HIP_MEMORY_SCOPE_AGENT);
}
__device__ __forceinline__ u64t ld_u64(const u64t* p) {
    return __hip_atomic_load(p, __ATOMIC_RELAXED, __HIP_MEMORY_SCOPE_AGENT);
}
__device__ __forceinline__ void st_u64(u64t* p, u64t v) {
    __hip_atomic_store(p, v, __ATOMIC_RELAXED, __HIP_MEMORY_SCOPE_AGENT);
}
__device__ __forceinline__ uint8_t to_fp8(float v) {
    return (uint8_t)(__builtin_amdgcn_cvt_pk_fp8_f32(v, v, 0u, false) & 0xffu);
}

__global__ void init_flags(uint32_t* ws) {
    int i = blockIdx.x * 256 + threadIdx.x;
    if (i < 8192) ws[i] = 0u;
}

// Pre-arm the whole ring with the sentinel pattern.
__global__ void fill_ring(u64t* __restrict__ ring, long n) {
    long i = (long)blockIdx.x * 256 + threadIdx.x;
    if (i < n) ring[i] = SENT64;
}

// mlp1: h0 as f16 in [t][word][j][b&3] layout (word = b>>2), ring-compatible.
__global__ void mlp1_kernel(const float* __restrict__ x, const float* __restrict__ W1,
                            const float* __restrict__ b1, uint16_t* __restrict__ h0h) {
    int idx = blockIdx.x * 256 + threadIdx.x;
    if (idx >= B * T * H) return;
    int j  = idx % H;
    int bt = idx / H;          // bt = b*T + t
    int b  = bt / T;
    int t  = bt % T;
    const float* xr = x  + (size_t)bt * DIN;
    const float* wr = W1 + (size_t)j * DIN;
    float a = b1[j];
#pragma unroll
    for (int k = 0; k < DIN; ++k) a += xr[k] * wr[k];
    _Float16 h = (_Float16)a;
    h0h[((size_t)(t * 2 + (b >> 2)) * H + j) * 4 + (b & 3)] = __builtin_bit_cast(uint16_t, h);
}

// All weights fp8 e4m3. One thread per (l, g, frag, lane); writes u64 (8 fp8).
// frag f = kt*13+nt; element j: r = g*200 + nt*16 + (lane&15),
// k = kt*32 + (lane>>4)*8 + j ; Wcat[r][k] = k<200 ? Wih : Whh[k-200]; 0 pad.
__global__ void convert_weights_mfma(const float* __restrict__ Wih,
                                     const float* __restrict__ Whh,
                                     u64t* __restrict__ Wm8) {
    size_t idx = (size_t)blockIdx.x * 256 + threadIdx.x;
    const size_t TOT = (size_t)L * 4 * NFRAG * 64;
    if (idx >= TOT) return;
    int lane = (int)(idx & 63);
    size_t r0 = idx >> 6;
    int f = (int)(r0 % NFRAG); r0 /= NFRAG;
    int g = (int)(r0 % 4);
    int l = (int)(r0 / 4);
    int kt = f / 13, nt = f % 13;
    int rl = nt * 16 + (lane & 15);
    int r  = g * 200 + rl;
    float v[8];
#pragma unroll
    for (int j = 0; j < 8; ++j) {
        int k = kt * 32 + (lane >> 4) * 8 + j;
        float xx = 0.0f;
        if (rl < 200 && k < 400)
            xx = (k < 200) ? Wih[((size_t)l * G + r) * 200 + k]
                           : Whh[((size_t)l * G + r) * 200 + (k - 200)];
        v[j] = xx;
    }
    uint32_t lo = __builtin_amdgcn_cvt_pk_fp8_f32(v[0], v[1], 0u, false);
    lo = __builtin_amdgcn_cvt_pk_fp8_f32(v[2], v[3], lo, true);
    uint32_t hi = __builtin_amdgcn_cvt_pk_fp8_f32(v[4], v[5], 0u, false);
    hi = __builtin_amdgcn_cvt_pk_fp8_f32(v[6], v[7], hi, true);
    Wm8[((size_t)(l * 4 + g) * NFRAG + f) * 64 + lane] = (u64t)lo | ((u64t)hi << 32);
}

#define MFMA8(a, b, c)  __builtin_amdgcn_mfma_f32_16x16x32_fp8_fp8((a), (b), (c), 0, 0, 0)
#define LDA8(kt) (*(const long*)&xh8[(lane & 15) * XPAD + (kt) * 32 + (lane >> 4) * 8])

// Fast-path worker: one wave = (gate g, nt-slice [NTB, NTB+NTN)).
// 8 waves/WG -> 2 waves/SIMD (TLP hides LDS/exp/poll/barrier stalls).
template <int NTB, int NTN>
__device__ __forceinline__ void run_fast(
    int l, int tid, int g, int lane, int R,
    const u64t* __restrict__ wq8,
    u64t* wl8, uint8_t* xh8, float* zl,
    const u64t* __restrict__ h0h, u64t* ring, float* finalbuf, uint32_t* flags,
    const float* __restrict__ bih, const float* __restrict__ bhh)
{
#pragma clang fp contract(fast)
    const int rmask = R - 1;
    const int word  = tid / 200;          // 0/1 for tid<400
    const int j     = tid - word * 200;
    const bool act  = tid < 400;

    float cs[4];
    float bs[4];
    if (act) {
#pragma unroll
        for (int gg = 0; gg < 4; ++gg)
            bs[gg] = bih[(size_t)l * G + gg * H + j] + bhh[(size_t)l * G + gg * H + j];
#pragma unroll
        for (int b = 0; b < 4; ++b) cs[b] = 0.0f;
    }

    // register weights: kt 0..8, this wave's nt slice
    u64t wr[9 * NTN];
#pragma unroll
    for (int kt = 0; kt < 9; ++kt)
#pragma unroll
        for (int n = 0; n < NTN; ++n)
            wr[kt * NTN + n] = wq8[(kt * 13 + NTB + n) * 64 + lane];
    // LDS weights kt 9..12: loaded once by the half==0 waves (full gate range)
    if (NTB == 0) {
        for (int i = 0; i < F_LD; ++i)
            wl8[(g * F_LD + i) * 64 + lane] = wq8[(F_RG + i) * 64 + lane];
    }
    __syncthreads();

    for (int t = 0; t < T; ++t) {
        f32x4 acc[NTN];
#pragma unroll
        for (int n = 0; n < NTN; ++n) acc[n] = (f32x4){0.f, 0.f, 0.f, 0.f};

        // ---- h-part: kt 7..8 (reg) -- own h_{t-1}, overlaps producer ----
#pragma unroll
        for (int kt = 7; kt < 9; ++kt) {
            long a = LDA8(kt);
#pragma unroll
            for (int n = 0; n < NTN; ++n)
                acc[n] = MFMA8(a, (long)wr[kt * NTN + n], acc[n]);
        }
        // ---- h-part: kt 9..12 (LDS) ----
#pragma unroll
        for (int kt = 9; kt < 13; ++kt) {
            long a = LDA8(kt);
#pragma unroll
            for (int n = 0; n < NTN; ++n) {
                u64t w = wl8[(g * F_LD + (kt - 9) * 13 + NTB + n) * 64 + lane];
                acc[n] = MFMA8(a, (long)w, acc[n]);
            }
        }

        // ---- backpressure ----
        if (l < L - 1 && t >= R) {
            const uint32_t need = (uint32_t)(t - R + 1);
            while (ld_flag(&flags[CFLAG(l + 1)]) < need) __builtin_amdgcn_s_sleep(1);
        }

        // ---- stage x_t: 1 u64/thread, sentinel protocol ----
        if (act) {
            u64t p;
            if (l == 0) {
                p = h0h[(size_t)t * 400 + tid];
            } else {
                u64t* s = ring + ((size_t)(l - 1) * R + (t & rmask)) * 400 + tid;
                p = ld_u64(s);
                while ((uint16_t)(p >> 48) == SENT16) {
                    __builtin_amdgcn_s_sleep(1);
                    p = ld_u64(s);
                }
                st_u64(s, SENT64);   // re-arm for next wrap
            }
#pragma unroll
            for (int bb = 0; bb < 4; ++bb) {
                float f = (float)__builtin_bit_cast(_Float16, (uint16_t)(p >> (16 * bb)));
                xh8[(word * 4 + bb) * XPAD + j] = to_fp8(f);
            }
        }
        __syncthreads();

        // ---- x-part: kt 0..6 (reg); kt6 = x 192..199 + own-h 200..223 ----
#pragma unroll
        for (int kt = 0; kt < 7; ++kt) {
            long a = LDA8(kt);
#pragma unroll
            for (int n = 0; n < NTN; ++n)
                acc[n] = MFMA8(a, (long)wr[kt * NTN + n], acc[n]);
        }

        // ---- zl write: D row m=(lane>>4)*4+r (batch), col nj ----
        if ((lane >> 4) < 2) {
#pragma unroll
            for (int n = 0; n < NTN; ++n) {
                int nj = (NTB + n) * 16 + (lane & 15);
#pragma unroll
                for (int r = 0; r < 4; ++r) {
                    int b = (lane >> 4) * 4 + r;
                    zl[(g * 8 + b) * 208 + nj] = acc[n][r];
                }
            }
        }
        // re-arm stores (issued at stage, long in flight) must be visible
        // before CFLAG publish; drain here overlaps nothing critical.
        asm volatile("s_waitcnt vmcnt(0)" ::: "memory");
        __syncthreads();
        if (tid == 0 && l > 0) st_flag(&flags[CFLAG(l)], (uint32_t)(t + 1));

        // ---- activation: 400 threads x 4 batches ----
        if (act) {
            u64t p = 0ull;
#pragma unroll
            for (int bb = 0; bb < 4; ++bb) {
                int b = word * 4 + bb;
                float zi = zl[(0 * 8 + b) * 208 + j] + bs[0];
                float zf = zl[(1 * 8 + b) * 208 + j] + bs[1];
                float zg = zl[(2 * 8 + b) * 208 + j] + bs[2];
                float zo = zl[(3 * 8 + b) * 208 + j] + bs[3];
                float ig = fsig(zi);
                float fg = fsig(zf);
                float gg = ftanh(zg);
                float og = fsig(zo);
                float c  = fg * cs[bb] + ig * gg;
                cs[bb] = c;
                float h = og * ftanh(c);
                xh8[b * XPAD + 200 + j] = to_fp8(h);
                _Float16 hh = (_Float16)h;
                p |= (u64t)__builtin_bit_cast(uint16_t, hh) << (16 * bb);
                if (l == L - 1) finalbuf[((size_t)b * T + t) * H + j] = h;
            }
            if (l < L - 1) {
                // fire-and-forget: data doubles as the readiness flag
                st_u64(ring + ((size_t)l * R + (t & rmask)) * 400 + tid, p);
            }
        }
        __syncthreads();   // xh8 h-cols stable for next h-GEMM
    }
}

// One workgroup per layer, 512 threads = 8 waves (2 per SIMD).
// Wave w: gate g = w&3, nt-half = w>>2 (nt 0..6 / 7..12).
// DATA-EMBEDDED HANDSHAKE (sentinel) + all-fp8 resident weights.
template <bool FAST>
__global__ __launch_bounds__(512, 2)
void lstm_pipeline(const u64t* __restrict__ Wm8,
                   const float* __restrict__ Wih, const float* __restrict__ Whh,
                   const float* __restrict__ bih, const float* __restrict__ bhh,
                   float* ws, int R) {
#pragma clang fp contract(fast)
    const int bx    = blockIdx.x;
    const int l     = ((bx & 7) * 25) + (bx >> 3);   // 25 consecutive layers per XCD
    const int tid   = threadIdx.x;
    const int wv    = tid >> 6;
    const int g     = wv & 3;
    const int half  = wv >> 2;
    const int lane  = tid & 63;
    const int rmask = R - 1;

    const u64t* h0h = (const u64t*)(ws + OFF_H0);
    float*    finalbuf = ws + OFF_FINAL;
    u64t*     ring     = (u64t*)(ws + OFF_RING);   // [slot][word][j][4b] f16, 400 u64/slot
    uint32_t* flags    = (uint32_t*)ws;

    __shared__ __align__(16) uint8_t  xh8[16 * XPAD];      // [m][k] fp8 A, k=0..415 (+pad)
    __shared__ __align__(16) float    zl[4 * 8 * 208];     // [g][b][nj]
    __shared__ __align__(16) u64t     wl8[4 * F_LD * 64];  // fp8 weight zone kt9..12

    // zero xh8 once: pad rows 8..15, pad cols 400.., and h-cols for t=0 (h_{-1}=0)
    for (int i = tid; i < (16 * XPAD) / 16; i += 512)
        ((uint4*)xh8)[i] = make_uint4(0u, 0u, 0u, 0u);

    if (FAST) {
        const u64t* wq8 = Wm8 + (size_t)(l * 4 + g) * NFRAG * 64;
        if (half == 0)
            run_fast<0, 7>(l, tid, g, lane, R, wq8, wl8, xh8, zl,
                           h0h, ring, finalbuf, flags, bih, bhh);
        else
            run_fast<7, 6>(l, tid, g, lane, R, wq8, wl8, xh8, zl,
                           h0h, ring, finalbuf, flags, bih, bhh);
        return;
    }

    // ---------------- f32 fallback (slow but correct-enough) ----------------
    float* xhf = (float*)wl8;   // f32 view [b*416 + col]
    const bool actj = tid < H;
    float cs[B];
    float bs[4];
    if (actj) {
#pragma unroll
        for (int gg = 0; gg < 4; ++gg)
            bs[gg] = bih[(size_t)l * G + gg * H + tid] + bhh[(size_t)l * G + gg * H + tid];
#pragma unroll
        for (int b = 0; b < B; ++b) cs[b] = 0.0f;
    }
    __syncthreads();

    for (int t = 0; t < T; ++t) {
        if (l < L - 1 && t >= R) {
            const uint32_t need = (uint32_t)(t - R + 1);
            while (ld_flag(&flags[CFLAG(l + 1)]) < need) __builtin_amdgcn_s_sleep(1);
        }
        if (actj) {
            u64t p0, p1;
            if (l == 0) {
                p0 = h0h[(size_t)t * 400 + tid];
                p1 = h0h[(size_t)t * 400 + 200 + tid];
            } else {
                u64t* s = ring + ((size_t)(l - 1) * R + (t & rmask)) * 400;
                p0 = ld_u64(s + tid);
                p1 = ld_u64(s + 200 + tid);
                while ((uint16_t)(p0 >> 48) == SENT16 ||
                       (uint16_t)(p1 >> 48) == SENT16) {
                    __builtin_amdgcn_s_sleep(1);
                    p0 = ld_u64(s + tid);
                    p1 = ld_u64(s + 200 + tid);
                }
                st_u64(s + tid, SENT64);
                st_u64(s + 200 + tid, SENT64);
            }
#pragma unroll
            for (int b = 0; b < 4; ++b) {
                xhf[b * 416 + tid]       = (float)__builtin_bit_cast(_Float16, (uint16_t)(p0 >> (16 * b)));
                xhf[(b + 4) * 416 + tid] = (float)__builtin_bit_cast(_Float16, (uint16_t)(p1 >> (16 * b)));
            }
        }
        asm volatile("s_waitcnt vmcnt(0)" ::: "memory");
        __syncthreads();
        if (tid == 0 && l > 0) st_flag(&flags[CFLAG(l)], (uint32_t)(t + 1));

        if (actj) {
            const float* wi0 = Wih + (size_t)l * G * H;
            const float* wh0 = Whh + (size_t)l * G * H;
            float acc[4][B];
#pragma unroll
            for (int gg = 0; gg < 4; ++gg)
#pragma unroll
                for (int b = 0; b < B; ++b) acc[gg][b] = 0.0f;
            for (int k2 = 0; k2 < 200; ++k2) {
                float2 wvv[4];
                if (k2 < 100) {
#pragma unroll
                    for (int gg = 0; gg < 4; ++gg)
                        wvv[gg] = *(const float2*)&wi0[((size_t)(gg * 200 + tid)) * 200 + 2 * k2];
                } else {
#pragma unroll
                    for (int gg = 0; gg < 4; ++gg)
                        wvv[gg] = *(const float2*)&wh0[((size_t)(gg * 200 + tid)) * 200 + 2 * (k2 - 100)];
                }
#pragma unroll
                for (int b = 0; b < B; ++b) {
                    float2 xv = *(const float2*)&xhf[b * 416 + 2 * k2];
#pragma unroll
                    for (int gg = 0; gg < 4; ++gg) {
                        acc[gg][b] += wvv[gg].x * xv.x;
                        acc[gg][b] += wvv[gg].y * xv.y;
                    }
                }
            }
#pragma unroll
            for (int gg = 0; gg < 4; ++gg)
#pragma unroll
                for (int b = 0; b < B; ++b)
                    zl[(gg * 8 + b) * 208 + tid] = acc[gg][b];
        }
        __syncthreads();

        if (actj) {
            u64t p0 = 0ull, p1 = 0ull;
#pragma unroll
            for (int b = 0; b < B; ++b) {
                float zi = zl[(0 * 8 + b) * 208 + tid] + bs[0];
                float zf = zl[(1 * 8 + b) * 208 + tid] + bs[1];
                float zg = zl[(2 * 8 + b) * 208 + tid] + bs[2];
                float zo = zl[(3 * 8 + b) * 208 + tid] + bs[3];
                float ig = fsig(zi);
                float fg = fsig(zf);
                float gg = ftanh(zg);
                float og = fsig(zo);
                float c  = fg * cs[b] + ig * gg;
                cs[b] = c;
                float h = og * ftanh(c);
                xhf[b * 416 + 200 + tid] = h;
                _Float16 hh = (_Float16)h;
                u64t u = (u64t)__builtin_bit_cast(uint16_t, hh);
                if (b < 4) p0 |= u << (16 * b);
                else       p1 |= u << (16 * (b - 4));
                if (l == L - 1) finalbuf[((size_t)b * T + t) * H + tid] = h;
            }
            if (l < L - 1) {
                u64t* dst = ring + ((size_t)l * R + (t & rmask)) * 400;
                st_u64(dst + tid, p0);
                st_u64(dst + 200 + tid, p1);
            }
        }
        __syncthreads();
    }
}

__global__ __launch_bounds__(64)
void mlp2_kernel(const float* __restrict__ fin, const float* __restrict__ W2a,
                 const float* __restrict__ b2a, const float* __restrict__ W2b,
                 const float* __restrict__ b2b, float* __restrict__ out) {
    const int bt  = blockIdx.x;   // b*T + t
    const int tid = threadIdx.x;
    __shared__ float sx[H];
    __shared__ float sh[50];
    for (int i = tid; i < H; i += 64) sx[i] = fin[(size_t)bt * H + i];
    __syncthreads();
    if (tid < 50) {
        float a = b2a[tid];
        const float* w = W2a + (size_t)tid * H;
        for (int k = 0; k < H; ++k) a += w[k] * sx[k];
        sh[tid] = fmaxf(a, 0.0f);
    }
    __syncthreads();
    if (tid < 24) {
        float a = b2b[tid];
        const float* w = W2b + (size_t)tid * 50;
#pragma unroll
        for (int m = 0; m < 50; ++m) a += w[m] * sh[m];
        out[(size_t)bt * 24 + tid] = a;
    }
}

extern "C" void kernel_launch(void* const* d_in, const int* in_sizes, int n_in,
                              void* d_out, int out_size, void* d_ws, size_t ws_size,
                              hipStream_t stream) {
    const float* x    = (const float*)d_in[0];
    const float* W1   = (const float*)d_in[1];
    const float* b1   = (const float*)d_in[2];
    const float* Wih  = (const float*)d_in[3];
    const float* Whh  = (const float*)d_in[4];
    const float* bihp = (const float*)d_in[5];
    const float* bhhp = (const float*)d_in[6];
    const float* W2a  = (const float*)d_in[7];
    const float* b2a  = (const float*)d_in[8];
    const float* W2b  = (const float*)d_in[9];
    const float* b2b  = (const float*)d_in[10];
    float* out = (float*)d_out;
    float* ws  = (float*)d_ws;

    // fp8 zone: L*4*169 frags * 64 lanes * 8 B = 69.2 MB
    const size_t wm8_u32 = (size_t)L * 4 * NFRAG * 64 * 2;
    const size_t ring_u32_per_R = (size_t)(L - 1) * B * H / 2;  // f16 ring per R unit

    int R = 8; bool fast = false; size_t offwm = 0;
    for (;;) {
        size_t o = (OFF_RING + (size_t)R * ring_u32_per_R + 3) & ~(size_t)3;  // 16B align
        if ((o + wm8_u32) * 4ull <= ws_size) { fast = true; offwm = o; break; }
        if (R == 1) break;
        R >>= 1;
    }
    if (!fast) {
        R = 8;
        while (R > 1 && (OFF_RING + (size_t)R * ring_u32_per_R) * 4ull > ws_size)
            R >>= 1;
    }
    u64t* Wm8 = (u64t*)(ws + offwm);

    const long ring_u64 = (long)(L - 1) * R * 400;   // u64 words in the ring

    init_flags<<<32, 256, 0, stream>>>((uint32_t*)d_ws);
    fill_ring<<<(int)((ring_u64 + 255) / 256), 256, 0, stream>>>(
        (u64t*)(ws + OFF_RING), ring_u64);
    mlp1_kernel<<<(B * T * H + 255) / 256, 256, 0, stream>>>(x, W1, b1,
                                                             (uint16_t*)(ws + OFF_H0));
    if (fast) {
        const size_t conv_threads = (size_t)L * 4 * NFRAG * 64;
        convert_weights_mfma<<<(int)((conv_threads + 255) / 256), 256, 0, stream>>>(
            Wih, Whh, Wm8);
        lstm_pipeline<true><<<L, 512, 0, stream>>>(Wm8, Wih, Whh, bihp, bhhp, ws, R);
    } else {
        lstm_pipeline<false><<<L, 512, 0, stream>>>(Wm8, Wih, Whh, bihp, bhhp, ws, R);
    }
    mlp2_kernel<<<B * T, 64, 0, stream>>>(ws + OFF_FINAL, W2a, b2a, W2b, b2b, out);
}